// Round 8
// baseline (2104.440 us; speedup 1.0000x reference)
//
#include <hip/hip_runtime.h>
#include <math.h>

#define N_NODES 100000
#define R_REL   3
#define E_EDGES 1600000
#define HID     64
#define DFLAT   129
#define KTOP    30
#define NC1     16
#define NC2     32
#define KSZ     5
#define NG      64
#define CAP     2048
#define SLOTS   8     // CAP / 256
#define TOUT    11    // K/2 - KS + 1
#define NBLK    391   // ceil(N_NODES/256)
#define NB      391   // coarse buckets (dst>>8)
#define BCAP    4608  // per-bucket capacity (mean 4092, +8 sigma)

// ---------------- utility ----------------
__global__ void zero_f32(float* p, int n) {
    int i = blockIdx.x * blockDim.x + threadIdx.x;
    int stride = gridDim.x * blockDim.x;
    for (; i < n; i += stride) p[i] = 0.0f;
}

__global__ void zero_i32(int* p, int n) {
    int i = blockIdx.x * blockDim.x + threadIdx.x;
    if (i < n) p[i] = 0;
}

// ---------------- CSR rowptr build ----------------
__global__ void hist_kernel(const int* __restrict__ dst, int* __restrict__ cnt, int e) {
    int i = blockIdx.x * blockDim.x + threadIdx.x;
    if (i < e) atomicAdd(&cnt[dst[i]], 1);
}

__global__ void block_sum(const int* __restrict__ cnt, int* __restrict__ bsum, int n) {
    __shared__ int s[256];
    int i = blockIdx.x * 256 + threadIdx.x;
    s[threadIdx.x] = i < n ? cnt[i] : 0;
    __syncthreads();
    for (int o = 128; o > 0; o >>= 1) {
        if (threadIdx.x < o) s[threadIdx.x] += s[threadIdx.x + o];
        __syncthreads();
    }
    if (threadIdx.x == 0) bsum[blockIdx.x] = s[0];
}

__global__ void __launch_bounds__(512) scan_bsum(int* bsum, int nb) {
    __shared__ int s[512];
    int t = threadIdx.x;
    int orig = t < nb ? bsum[t] : 0;
    s[t] = orig;
    __syncthreads();
    for (int o = 1; o < 512; o <<= 1) {
        int v = t >= o ? s[t - o] : 0;
        __syncthreads();
        s[t] += v;
        __syncthreads();
    }
    if (t < nb) bsum[t] = s[t] - orig;   // exclusive
}

__global__ void scan_blocks(const int* __restrict__ cnt, const int* __restrict__ boff,
                            int* __restrict__ rowptr, int n) {
    __shared__ int s[256];
    int b = blockIdx.x, t = threadIdx.x;
    int i = b * 256 + t;
    s[t] = i < n ? cnt[i] : 0;
    __syncthreads();
    for (int o = 1; o < 256; o <<= 1) {
        int u = t >= o ? s[t - o] : 0;
        __syncthreads();
        s[t] += u;
        __syncthreads();
    }
    if (i < n) rowptr[i + 1] = s[t] + boff[b];
    if (i == 0) rowptr[0] = 0;
}

// ---------------- two-phase binned permutation build ----------------
// phase 1: bin edges by dst>>8 into NB coarse buckets; writes are ~streaming
// (<=NB contiguous streams). Order within bucket is arbitrary (sort_rows fixes).
__global__ void __launch_bounds__(256) bin_stage(const int* __restrict__ dst,
                                                 const int* __restrict__ src,
                                                 const float* __restrict__ ew,
                                                 int* __restrict__ gcur,
                                                 int4* __restrict__ staged, int e) {
    __shared__ int hist[NB];
    __shared__ int base[NB];
    __shared__ int lcur[NB];
    int t = threadIdx.x;
    for (int j = t; j < NB; j += 256) { hist[j] = 0; lcur[j] = 0; }
    __syncthreads();
    int i = blockIdx.x * 256 + t;
    int d = 0, bin = -1;
    if (i < e) { d = dst[i]; bin = d >> 8; atomicAdd(&hist[bin], 1); }
    __syncthreads();
    for (int j = t; j < NB; j += 256)
        if (hist[j] > 0) base[j] = atomicAdd(&gcur[j], hist[j]);
    __syncthreads();
    if (i < e) {
        int r = atomicAdd(&lcur[bin], 1);
        int pos = base[bin] + r;
        if (pos < BCAP)
            staged[(size_t)bin * BCAP + pos] = make_int4(d, i, src[i], __float_as_int(ew[i]));
    }
}

// phase 2: one block per bucket; per-dst cursors in LDS; final writes land in a
// ~48 KB window per bucket (cacheline-resident). No global atomics.
__global__ void __launch_bounds__(256) bin_scatter(const int* __restrict__ gcur,
                                                   const int4* __restrict__ staged,
                                                   const int* __restrict__ rowptr,
                                                   int* __restrict__ col,
                                                   float* __restrict__ ewp,
                                                   int* __restrict__ eorig, int n) {
    __shared__ int cur[256];
    int b = blockIdx.x, t = threadIdx.x;
    int node = b * 256 + t;
    cur[t] = (node < n) ? rowptr[node] : 0;
    __syncthreads();
    int nb = gcur[b];
    if (nb > BCAP) nb = BCAP;
    for (int i = t; i < nb; i += 256) {
        int4 v = staged[(size_t)b * BCAP + i];
        int p = atomicAdd(&cur[v.x & 255], 1);
        col[p] = v.z;
        ewp[p] = __int_as_float(v.w);
        eorig[p] = v.y;
    }
}

// stable order: sort each row's slots by original edge index so per-row
// accumulation matches numpy's edge-order sums (top-k selection stability).
__global__ void sort_rows(const int* __restrict__ rowptr, int* __restrict__ col,
                          float* __restrict__ ewp, int* __restrict__ eorig, int n) {
    int i = blockIdx.x * blockDim.x + threadIdx.x;
    if (i >= n) return;
    int r0 = rowptr[i], r1 = rowptr[i + 1];
    for (int a = r0 + 1; a < r1; ++a) {
        int ke = eorig[a]; int kc = col[a]; float kw = ewp[a];
        int b = a - 1;
        while (b >= r0 && eorig[b] > ke) {
            eorig[b + 1] = eorig[b]; col[b + 1] = col[b]; ewp[b + 1] = ewp[b];
            --b;
        }
        eorig[b + 1] = ke; col[b + 1] = kc; ewp[b + 1] = kw;
    }
}

__global__ void deg_dinv(const int* __restrict__ rowptr, const float* __restrict__ ewp,
                         float* __restrict__ dinv, int n) {
    int i = blockIdx.x * blockDim.x + threadIdx.x;
    if (i < n) {
        float s = 0.0f;
        int r1 = rowptr[i + 1];
        for (int e = rowptr[i]; e < r1; ++e) s += ewp[e];
        dinv[i] = 1.0f / sqrtf(s + 1.0f);
    }
}

__global__ void enorm_csr(const int* __restrict__ rowptr, const int* __restrict__ col,
                          const float* __restrict__ ewp, const float* __restrict__ dinv,
                          float* __restrict__ enormp, int n) {
    int i = blockIdx.x * blockDim.x + threadIdx.x;
    if (i < n) {
        float di = dinv[i];
        int r1 = rowptr[i + 1];
        for (int e = rowptr[i]; e < r1; ++e)
            enormp[e] = dinv[col[e]] * ewp[e] * di;
    }
}

// ---------------- register-tiled GEMM: out[n,64] = X[n,Kd] @ W[Kd,64] ----------
template<int Kd>
__global__ void __launch_bounds__(256) gemm_tile(const float* __restrict__ X,
                                                 const float* __restrict__ W,
                                                 float* __restrict__ out, int n) {
    __shared__ float sW[Kd * 64];
    const int tid = threadIdx.x;
    for (int t = tid; t < Kd * 16; t += 256)
        ((float4*)sW)[t] = ((const float4*)W)[t];
    __syncthreads();

    const int cq = tid >> 6;
    const int rg = tid & 63;
    const int row0 = blockIdx.x * 256 + rg * 4;
    const float4* sW4 = (const float4*)sW;

    float4 acc[4][4];
    #pragma unroll
    for (int r = 0; r < 4; ++r)
        #pragma unroll
        for (int c = 0; c < 4; ++c) acc[r][c] = make_float4(0.f, 0.f, 0.f, 0.f);

    int rl[4];
    #pragma unroll
    for (int r = 0; r < 4; ++r) {
        int rr = row0 + r;
        rl[r] = rr < n ? rr : (n - 1);
    }

    for (int k0 = 0; k0 < Kd; k0 += 8) {
        float4 xa[4][2];
        #pragma unroll
        for (int r = 0; r < 4; ++r) {
            const float4* xp = (const float4*)(X + (size_t)rl[r] * Kd + k0);
            xa[r][0] = xp[0];
            xa[r][1] = xp[1];
        }
        #pragma unroll
        for (int kk = 0; kk < 8; ++kk) {
            float xk[4];
            #pragma unroll
            for (int r = 0; r < 4; ++r) {
                float4 h = xa[r][kk >> 2];
                xk[r] = (kk & 3) == 0 ? h.x : (kk & 3) == 1 ? h.y : (kk & 3) == 2 ? h.z : h.w;
            }
            #pragma unroll
            for (int c = 0; c < 4; ++c) {
                float4 w4 = sW4[(k0 + kk) * 16 + cq * 4 + c];
                #pragma unroll
                for (int r = 0; r < 4; ++r) {
                    acc[r][c].x += xk[r] * w4.x;
                    acc[r][c].y += xk[r] * w4.y;
                    acc[r][c].z += xk[r] * w4.z;
                    acc[r][c].w += xk[r] * w4.w;
                }
            }
        }
    }

    #pragma unroll
    for (int r = 0; r < 4; ++r) {
        int rr = row0 + r;
        if (rr < n) {
            float4* op = (float4*)(out + (size_t)rr * 64 + cq * 16);
            #pragma unroll
            for (int c = 0; c < 4; ++c) op[c] = acc[r][c];
        }
    }
}

// -------- fused CSR aggregation (64 feats): one wave per dst row, lane = feat --------
__global__ void __launch_bounds__(256) agg64_fused(const int* __restrict__ rowptr,
                                                   const int* __restrict__ col,
                                                   const float* __restrict__ enormp,
                                                   const float* __restrict__ hpre,
                                                   const float* __restrict__ dinv,
                                                   const float* __restrict__ bias,
                                                   float* __restrict__ hout, int n) {
    int gid = blockIdx.x * 256 + threadIdx.x;
    int row = gid >> 6;
    int lane = gid & 63;
    if (row >= n) return;
    int r0 = rowptr[row], r1 = rowptr[row + 1];
    float acc = 0.0f;
    for (int base = r0; base < r1; base += 64) {
        int e = base + lane;
        int cv = 0; float ev = 0.0f;
        if (e < r1) { cv = col[e]; ev = enormp[e]; }
        int m = r1 - base; if (m > 64) m = 64;
        int j = 0;
        for (; j + 8 <= m; j += 8) {
            int   s0 = __shfl(cv, j, 64),     s1 = __shfl(cv, j + 1, 64);
            int   s2 = __shfl(cv, j + 2, 64), s3 = __shfl(cv, j + 3, 64);
            int   s4 = __shfl(cv, j + 4, 64), s5 = __shfl(cv, j + 5, 64);
            int   s6 = __shfl(cv, j + 6, 64), s7 = __shfl(cv, j + 7, 64);
            float c0 = __shfl(ev, j, 64),     c1 = __shfl(ev, j + 1, 64);
            float c2 = __shfl(ev, j + 2, 64), c3 = __shfl(ev, j + 3, 64);
            float c4 = __shfl(ev, j + 4, 64), c5 = __shfl(ev, j + 5, 64);
            float c6 = __shfl(ev, j + 6, 64), c7 = __shfl(ev, j + 7, 64);
            float v0 = hpre[(size_t)s0 * 64 + lane];
            float v1 = hpre[(size_t)s1 * 64 + lane];
            float v2 = hpre[(size_t)s2 * 64 + lane];
            float v3 = hpre[(size_t)s3 * 64 + lane];
            float v4 = hpre[(size_t)s4 * 64 + lane];
            float v5 = hpre[(size_t)s5 * 64 + lane];
            float v6 = hpre[(size_t)s6 * 64 + lane];
            float v7 = hpre[(size_t)s7 * 64 + lane];
            acc += c0 * v0; acc += c1 * v1; acc += c2 * v2; acc += c3 * v3;
            acc += c4 * v4; acc += c5 * v5; acc += c6 * v6; acc += c7 * v7;
        }
        for (; j + 4 <= m; j += 4) {
            int   s0 = __shfl(cv, j, 64),     s1 = __shfl(cv, j + 1, 64);
            int   s2 = __shfl(cv, j + 2, 64), s3 = __shfl(cv, j + 3, 64);
            float c0 = __shfl(ev, j, 64),     c1 = __shfl(ev, j + 1, 64);
            float c2 = __shfl(ev, j + 2, 64), c3 = __shfl(ev, j + 3, 64);
            float v0 = hpre[(size_t)s0 * 64 + lane];
            float v1 = hpre[(size_t)s1 * 64 + lane];
            float v2 = hpre[(size_t)s2 * 64 + lane];
            float v3 = hpre[(size_t)s3 * 64 + lane];
            acc += c0 * v0; acc += c1 * v1; acc += c2 * v2; acc += c3 * v3;
        }
        for (; j < m; ++j) {
            int s = __shfl(cv, j, 64);
            float coef = __shfl(ev, j, 64);
            acc += coef * hpre[(size_t)s * 64 + lane];
        }
    }
    float dv = dinv[row];
    hout[gid] = tanhf(acc + dv * dv * hpre[(size_t)row * 64 + lane] + bias[lane]);
}

// ---------------- h2 @ W2 (64 -> 1), one wave per row ----------------
__global__ void gemv64(const float* __restrict__ h, const float* __restrict__ w,
                       float* __restrict__ out, int n) {
    int gid = blockIdx.x * blockDim.x + threadIdx.x;
    int row = gid >> 6;
    int lane = gid & 63;
    if (row >= n) return;
    float v = h[(size_t)row * 64 + lane] * w[lane];
    for (int off = 32; off > 0; off >>= 1) v += __shfl_down(v, off, 64);
    if (lane == 0) out[row] = v;
}

// -------- fused CSR aggregation (1 feat): one thread per dst row --------
__global__ void agg1_fused(const int* __restrict__ rowptr, const int* __restrict__ col,
                           const float* __restrict__ enormp, const float* __restrict__ hpre3,
                           const float* __restrict__ dinv, const float* __restrict__ b2,
                           float* __restrict__ h3, int n) {
    int i = blockIdx.x * blockDim.x + threadIdx.x;
    if (i >= n) return;
    float acc = 0.0f;
    int r1 = rowptr[i + 1];
    for (int e = rowptr[i]; e < r1; ++e) acc += enormp[e] * hpre3[col[e]];
    float dv = dinv[i];
    h3[i] = tanhf(acc + dv * dv * hpre3[i] + b2[0]);
}

// ---------------- group compaction: deterministic counting sort ----------------
__global__ void __launch_bounds__(256) grp_hist(const int* __restrict__ group,
                                                int* __restrict__ bcnt, int n) {
    __shared__ int lh[NG];
    int b = blockIdx.x, t = threadIdx.x;
    if (t < NG) lh[t] = 0;
    __syncthreads();
    int i = b * 256 + t;
    if (i < n) atomicAdd(&lh[group[i]], 1);
    __syncthreads();
    if (t < NG) bcnt[t * NBLK + b] = lh[t];
}

__global__ void __launch_bounds__(512) grp_scan(const int* __restrict__ bcnt,
                                                int* __restrict__ boff,
                                                int* __restrict__ cnt) {
    __shared__ int s[512];
    int g = blockIdx.x, t = threadIdx.x;
    int orig = t < NBLK ? bcnt[g * NBLK + t] : 0;
    s[t] = orig;
    __syncthreads();
    for (int o = 1; o < 512; o <<= 1) {
        int v = t >= o ? s[t - o] : 0;
        __syncthreads();
        s[t] += v;
        __syncthreads();
    }
    if (t < NBLK) boff[g * NBLK + t] = s[t] - orig;
    if (t == 511) cnt[g] = s[NBLK - 1] > CAP ? CAP : s[NBLK - 1];
}

__global__ void __launch_bounds__(256) grp_fill(const int* __restrict__ group,
                                                const int* __restrict__ boff,
                                                int* __restrict__ lists, int n) {
    __shared__ int lcur[NG];
    int b = blockIdx.x, t = threadIdx.x;
    if (t < NG) lcur[t] = 0;
    __syncthreads();
    int i = b * 256 + t;
    if (i < n) {
        int g = group[i];
        int p = atomicAdd(&lcur[g], 1);
        int pos = boff[g * NBLK + b] + p;
        if (pos < CAP) lists[g * CAP + pos] = i;
    }
}

// ---------------- per-group top-K by h3: iterative selection in registers ----------
__device__ __forceinline__ unsigned int fkey(float v) {
    unsigned int b = __float_as_uint(v);
    return (b & 0x80000000u) ? ~b : (b | 0x80000000u);
}

__global__ void __launch_bounds__(256) topk_kernel(const int* __restrict__ cnt,
                                                   const int* __restrict__ lists,
                                                   const float* __restrict__ h3,
                                                   int* __restrict__ topk) {
    __shared__ unsigned long long wmax[4];
    __shared__ unsigned long long winner;
    int g = blockIdx.x;
    int tid = threadIdx.x;
    int lane = tid & 63, wid = tid >> 6;
    int c = cnt[g];
    if (c > CAP) c = CAP;

    unsigned long long key[SLOTS];
    #pragma unroll
    for (int s = 0; s < SLOTS; ++s) {
        int e = s * 256 + tid;
        if (e < c) {
            int node = lists[g * CAP + e];
            key[s] = ((unsigned long long)fkey(h3[node]) << 32) | (unsigned int)(~node);
        } else {
            key[s] = 0ull;
        }
    }

    for (int k = 0; k < KTOP; ++k) {
        unsigned long long best = 0ull;
        #pragma unroll
        for (int s = 0; s < SLOTS; ++s) best = key[s] > best ? key[s] : best;
        #pragma unroll
        for (int off = 32; off > 0; off >>= 1) {
            unsigned long long o = __shfl_down(best, off, 64);
            best = o > best ? o : best;
        }
        if (lane == 0) wmax[wid] = best;
        __syncthreads();
        if (tid == 0) {
            unsigned long long b = wmax[0];
            for (int w = 1; w < 4; ++w) b = wmax[w] > b ? wmax[w] : b;
            winner = b;
            topk[g * KTOP + k] = ~(int)(unsigned int)b;
        }
        __syncthreads();
        unsigned long long w = winner;
        #pragma unroll
        for (int s = 0; s < SLOTS; ++s) if (key[s] == w) key[s] = 0ull;
        __syncthreads();
    }
}

// ---------------- fused sort-pool gather + conv1 + maxpool + conv2 ----------------
__global__ void __launch_bounds__(256) pool_conv(const float* __restrict__ h1,
                                                 const float* __restrict__ h2,
                                                 const float* __restrict__ h3,
                                                 const int* __restrict__ topk,
                                                 const float* __restrict__ c1w,
                                                 const float* __restrict__ c1b,
                                                 const float* __restrict__ c2w,
                                                 const float* __restrict__ c2b,
                                                 float* __restrict__ out) {
    __shared__ float sfeat[KTOP * DFLAT];
    __shared__ float sy[NC1 * KTOP];
    __shared__ float sm[NC1 * (KTOP / 2)];
    int g = blockIdx.x;
    int tid = threadIdx.x;

    for (int t = tid; t < KTOP * DFLAT; t += blockDim.x) {
        int k = t / DFLAT, d = t - k * DFLAT;
        int node = topk[g * KTOP + k];
        float v;
        if (d < 64)        v = h1[(size_t)node * 64 + d];
        else if (d < 128)  v = h2[(size_t)node * 64 + (d - 64)];
        else               v = h3[node];
        sfeat[t] = v;
    }
    __syncthreads();

    for (int t = tid; t < NC1 * KTOP; t += blockDim.x) {
        int c = t / KTOP, k = t - c * KTOP;
        float acc = c1b[c];
        const float* w = c1w + c * DFLAT;
        const float* f = sfeat + k * DFLAT;
        for (int d = 0; d < DFLAT; ++d) acc += f[d] * w[d];
        sy[c * KTOP + k] = fmaxf(acc, 0.0f);
    }
    __syncthreads();

    for (int t = tid; t < NC1 * (KTOP / 2); t += blockDim.x) {
        int c = t / (KTOP / 2), j = t - c * (KTOP / 2);
        sm[t] = fmaxf(sy[c * KTOP + 2 * j], sy[c * KTOP + 2 * j + 1]);
    }
    __syncthreads();

    for (int t = tid; t < NC2 * TOUT; t += blockDim.x) {
        int c2 = t / TOUT, tt = t - c2 * TOUT;
        float acc = c2b[c2];
        for (int c1i = 0; c1i < NC1; ++c1i) {
            const float* w = c2w + (c2 * NC1 + c1i) * KSZ;
            const float* m = sm + c1i * (KTOP / 2) + tt;
            for (int s = 0; s < KSZ; ++s) acc += m[s] * w[s];
        }
        out[g * NC2 * TOUT + t] += fmaxf(acc, 0.0f);
    }
}

// ---------------- host ----------------
static inline size_t align256(size_t x) { return (x + 255) & ~(size_t)255; }

extern "C" void kernel_launch(void* const* d_in, const int* in_sizes, int n_in,
                              void* d_out, int out_size, void* d_ws, size_t ws_size,
                              hipStream_t stream) {
    const float* x       = (const float*)d_in[0];
    const int*   eidx    = (const int*)d_in[1];    // [R,2,E]
    const float* ew      = (const float*)d_in[2];  // [R,E]
    const int*   group   = (const int*)d_in[3];    // [N]
    const float* W0      = (const float*)d_in[4];  // [R,128,64]
    const float* b0      = (const float*)d_in[5];
    const float* W1      = (const float*)d_in[6];  // [R,64,64]
    const float* b1      = (const float*)d_in[7];
    const float* W2      = (const float*)d_in[8];  // [R,64,1]
    const float* b2      = (const float*)d_in[9];
    const float* c1w     = (const float*)d_in[10];
    const float* c1b     = (const float*)d_in[11];
    const float* c2w     = (const float*)d_in[12];
    const float* c2b     = (const float*)d_in[13];
    float* out = (float*)d_out;

    char* ws = (char*)d_ws;
    size_t off = 0;
    float* dinv    = (float*)(ws + off); off = align256(off + (size_t)N_NODES * 4);
    int*   rowptr  = (int*)(ws + off);   off = align256(off + (size_t)(N_NODES + 1) * 4);
    int*   ccnt    = (int*)(ws + off);   off = align256(off + (size_t)N_NODES * 4);
    int*   bsum    = (int*)(ws + off);   off = align256(off + (size_t)512 * 4);
    int*   col     = (int*)(ws + off);   off = align256(off + (size_t)E_EDGES * 4);
    float* ewp     = (float*)(ws + off); off = align256(off + (size_t)E_EDGES * 4);
    int*   eorig   = (int*)(ws + off);   off = align256(off + (size_t)E_EDGES * 4);
    float* enormp  = (float*)(ws + off); off = align256(off + (size_t)E_EDGES * 4);
    float* hpre    = (float*)(ws + off); off = align256(off + (size_t)N_NODES * 64 * 4);
    float* h1      = (float*)(ws + off); off = align256(off + (size_t)N_NODES * 64 * 4);
    float* h2      = (float*)(ws + off); off = align256(off + (size_t)N_NODES * 64 * 4);
    float* hpre3   = (float*)(ws + off); off = align256(off + (size_t)N_NODES * 4);
    float* h3      = (float*)(ws + off); off = align256(off + (size_t)N_NODES * 4);
    int*   cnt     = (int*)(ws + off);   off = align256(off + (size_t)NG * 4);
    int*   lists   = (int*)(ws + off);   off = align256(off + (size_t)NG * CAP * 4);
    int*   topk    = (int*)(ws + off);   off = align256(off + (size_t)NG * KTOP * 4);
    int*   bcnt    = (int*)(ws + off);   off = align256(off + (size_t)NG * NBLK * 4);
    int*   boff    = (int*)(ws + off);   off = align256(off + (size_t)NG * NBLK * 4);
    int*   gcur    = (int*)(ws + off);   off = align256(off + (size_t)NB * 4);
    int4*  staged  = (int4*)(ws + off);  off = align256(off + (size_t)NB * BCAP * 16);
    (void)ws_size;

    const int B = 256;
    const int nOut = NG * NC2 * TOUT;
    const int gN   = (N_NODES + B - 1) / B;           // 391
    const int gE   = (E_EDGES + B - 1) / B;           // 6250
    const int gW   = (N_NODES * 64 + B - 1) / B;      // 25000
    const int gT   = (N_NODES + 255) / 256;           // gemm_tile

    zero_f32<<<(nOut + B - 1) / B, B, 0, stream>>>(out, nOut);

    // group compaction: deterministic counting sort, once per launch
    grp_hist<<<NBLK, B, 0, stream>>>(group, bcnt, N_NODES);
    grp_scan<<<NG, 512, 0, stream>>>(bcnt, boff, cnt);
    grp_fill<<<NBLK, B, 0, stream>>>(group, boff, lists, N_NODES);

    for (int r = 0; r < R_REL; ++r) {
        const int* src = eidx + (size_t)r * 2 * E_EDGES;
        const int* dst = src + E_EDGES;
        const float* ewr = ew + (size_t)r * E_EDGES;

        // ---- rowptr ----
        zero_i32<<<gN, B, 0, stream>>>(ccnt, N_NODES);
        hist_kernel<<<gE, B, 0, stream>>>(dst, ccnt, E_EDGES);
        block_sum<<<gN, B, 0, stream>>>(ccnt, bsum, N_NODES);
        scan_bsum<<<1, 512, 0, stream>>>(bsum, gN);
        scan_blocks<<<gN, B, 0, stream>>>(ccnt, bsum, rowptr, N_NODES);

        // ---- binned permutation build (cache-friendly) ----
        zero_i32<<<2, B, 0, stream>>>(gcur, NB);
        bin_stage<<<gE, B, 0, stream>>>(dst, src, ewr, gcur, staged, E_EDGES);
        bin_scatter<<<NB, B, 0, stream>>>(gcur, staged, rowptr, col, ewp, eorig, N_NODES);
        sort_rows<<<gN, B, 0, stream>>>(rowptr, col, ewp, eorig, N_NODES);
        deg_dinv<<<gN, B, 0, stream>>>(rowptr, ewp, dinv, N_NODES);
        enorm_csr<<<gN, B, 0, stream>>>(rowptr, col, ewp, dinv, enormp, N_NODES);

        // layer 1
        gemm_tile<128><<<gT, B, 0, stream>>>(x, W0 + (size_t)r * 128 * 64, hpre, N_NODES);
        agg64_fused<<<gW, B, 0, stream>>>(rowptr, col, enormp, hpre, dinv,
                                          b0 + (size_t)r * 64, h1, N_NODES);
        // layer 2
        gemm_tile<64><<<gT, B, 0, stream>>>(h1, W1 + (size_t)r * 64 * 64, hpre, N_NODES);
        agg64_fused<<<gW, B, 0, stream>>>(rowptr, col, enormp, hpre, dinv,
                                          b1 + (size_t)r * 64, h2, N_NODES);
        // layer 3
        gemv64<<<gW, B, 0, stream>>>(h2, W2 + (size_t)r * 64, hpre3, N_NODES);
        agg1_fused<<<gN, B, 0, stream>>>(rowptr, col, enormp, hpre3, dinv, b2 + r, h3, N_NODES);

        // sort pooling + convs
        topk_kernel<<<NG, B, 0, stream>>>(cnt, lists, h3, topk);
        pool_conv<<<NG, B, 0, stream>>>(h1, h2, h3, topk, c1w, c1b, c2w, c2b, out);
    }
}

// Round 9
// 2100.636 us; speedup vs baseline: 1.0018x; 1.0018x over previous
//
#include <hip/hip_runtime.h>
#include <math.h>

#define N_NODES 100000
#define R_REL   3
#define E_EDGES 1600000
#define HID     64
#define DFLAT   129
#define KTOP    30
#define NC1     16
#define NC2     32
#define KSZ     5
#define NG      64
#define CAP     2048
#define SLOTS   8     // CAP / 256
#define TOUT    11    // K/2 - KS + 1
#define NBLK    391   // ceil(N_NODES/256)
#define NB      391   // coarse buckets (dst>>8)
#define NCHUNK  512   // bin_stage blocks
#define CHSZ    3125  // E_EDGES / NCHUNK (exact)

// ---------------- utility ----------------
__global__ void zero_f32(float* p, int n) {
    int i = blockIdx.x * blockDim.x + threadIdx.x;
    int stride = gridDim.x * blockDim.x;
    for (; i < n; i += stride) p[i] = 0.0f;
}

__global__ void zero_i32(int* p, int n) {
    int i = blockIdx.x * blockDim.x + threadIdx.x;
    if (i < n) p[i] = 0;
}

// ---------------- CSR rowptr build ----------------
__global__ void hist_kernel(const int* __restrict__ dst, int* __restrict__ cnt, int e) {
    int i = blockIdx.x * blockDim.x + threadIdx.x;
    if (i < e) atomicAdd(&cnt[dst[i]], 1);
}

__global__ void block_sum(const int* __restrict__ cnt, int* __restrict__ bsum, int n) {
    __shared__ int s[256];
    int i = blockIdx.x * 256 + threadIdx.x;
    s[threadIdx.x] = i < n ? cnt[i] : 0;
    __syncthreads();
    for (int o = 128; o > 0; o >>= 1) {
        if (threadIdx.x < o) s[threadIdx.x] += s[threadIdx.x + o];
        __syncthreads();
    }
    if (threadIdx.x == 0) bsum[blockIdx.x] = s[0];
}

__global__ void __launch_bounds__(512) scan_bsum(int* bsum, int nb) {
    __shared__ int s[512];
    int t = threadIdx.x;
    int orig = t < nb ? bsum[t] : 0;
    s[t] = orig;
    __syncthreads();
    for (int o = 1; o < 512; o <<= 1) {
        int v = t >= o ? s[t - o] : 0;
        __syncthreads();
        s[t] += v;
        __syncthreads();
    }
    if (t < nb) bsum[t] = s[t] - orig;   // exclusive
}

__global__ void scan_blocks(const int* __restrict__ cnt, const int* __restrict__ boff,
                            int* __restrict__ rowptr, int n) {
    __shared__ int s[256];
    int b = blockIdx.x, t = threadIdx.x;
    int i = b * 256 + t;
    s[t] = i < n ? cnt[i] : 0;
    __syncthreads();
    for (int o = 1; o < 256; o <<= 1) {
        int u = t >= o ? s[t - o] : 0;
        __syncthreads();
        s[t] += u;
        __syncthreads();
    }
    if (i < n) rowptr[i + 1] = s[t] + boff[b];
    if (i == 0) rowptr[0] = 0;
}

// ---------------- two-phase binned permutation build ----------------
// phase 1 (chunked): each block owns CHSZ edges; LDS histogram over NB buckets,
// ONE global reservation per (block,bucket) against bcur (bucket-local cursor;
// global base comes exactly from rowptr), then positioned int4 writes. A block's
// edges for one bucket land consecutively -> coalesced lines.
__global__ void __launch_bounds__(256) bin_stage(const int* __restrict__ dst,
                                                 const int* __restrict__ src,
                                                 const float* __restrict__ ew,
                                                 const int* __restrict__ rowptr,
                                                 int* __restrict__ bcur,
                                                 int4* __restrict__ staged, int e) {
    __shared__ int hist[NB];
    __shared__ int base[NB];
    __shared__ int lcur[NB];
    int t = threadIdx.x;
    int e0 = blockIdx.x * CHSZ;
    int e1 = e0 + CHSZ; if (e1 > e) e1 = e;
    for (int j = t; j < NB; j += 256) { hist[j] = 0; lcur[j] = 0; }
    __syncthreads();
    for (int i = e0 + t; i < e1; i += 256)
        atomicAdd(&hist[dst[i] >> 8], 1);
    __syncthreads();
    for (int j = t; j < NB; j += 256) {
        int h = hist[j];
        if (h > 0) base[j] = rowptr[j << 8] + atomicAdd(&bcur[j], h);
    }
    __syncthreads();
    for (int i = e0 + t; i < e1; i += 256) {
        int d = dst[i];
        int bin = d >> 8;
        int r = atomicAdd(&lcur[bin], 1);
        staged[(size_t)(base[bin] + r)] = make_int4(d, i, src[i], __float_as_int(ew[i]));
    }
}

// phase 2: one block per bucket; per-dst cursors in LDS; final writes land in a
// ~48 KB window per bucket (cacheline-resident). No global atomics.
__global__ void __launch_bounds__(256) bin_scatter(const int4* __restrict__ staged,
                                                   const int* __restrict__ rowptr,
                                                   int* __restrict__ col,
                                                   float* __restrict__ ewp,
                                                   int* __restrict__ eorig, int n) {
    __shared__ int cur[256];
    int b = blockIdx.x, t = threadIdx.x;
    int node = b * 256 + t;
    cur[t] = (node < n) ? rowptr[node] : 0;
    __syncthreads();
    int s0 = rowptr[b << 8];
    int nend = (b + 1) << 8; if (nend > n) nend = n;
    int s1 = rowptr[nend];
    for (int i = s0 + t; i < s1; i += 256) {
        int4 v = staged[(size_t)i];
        int p = atomicAdd(&cur[v.x & 255], 1);
        col[p] = v.z;
        ewp[p] = __int_as_float(v.w);
        eorig[p] = v.y;
    }
}

// stable order: sort each row's slots by original edge index so per-row
// accumulation matches numpy's edge-order sums (top-k selection stability).
__global__ void sort_rows(const int* __restrict__ rowptr, int* __restrict__ col,
                          float* __restrict__ ewp, int* __restrict__ eorig, int n) {
    int i = blockIdx.x * blockDim.x + threadIdx.x;
    if (i >= n) return;
    int r0 = rowptr[i], r1 = rowptr[i + 1];
    for (int a = r0 + 1; a < r1; ++a) {
        int ke = eorig[a]; int kc = col[a]; float kw = ewp[a];
        int b = a - 1;
        while (b >= r0 && eorig[b] > ke) {
            eorig[b + 1] = eorig[b]; col[b + 1] = col[b]; ewp[b + 1] = ewp[b];
            --b;
        }
        eorig[b + 1] = ke; col[b + 1] = kc; ewp[b + 1] = kw;
    }
}

__global__ void deg_dinv(const int* __restrict__ rowptr, const float* __restrict__ ewp,
                         float* __restrict__ dinv, int n) {
    int i = blockIdx.x * blockDim.x + threadIdx.x;
    if (i < n) {
        float s = 0.0f;
        int r1 = rowptr[i + 1];
        for (int e = rowptr[i]; e < r1; ++e) s += ewp[e];
        dinv[i] = 1.0f / sqrtf(s + 1.0f);
    }
}

__global__ void enorm_csr(const int* __restrict__ rowptr, const int* __restrict__ col,
                          const float* __restrict__ ewp, const float* __restrict__ dinv,
                          float* __restrict__ enormp, int n) {
    int i = blockIdx.x * blockDim.x + threadIdx.x;
    if (i < n) {
        float di = dinv[i];
        int r1 = rowptr[i + 1];
        for (int e = rowptr[i]; e < r1; ++e)
            enormp[e] = dinv[col[e]] * ewp[e] * di;
    }
}

// ---------------- register-tiled GEMM: out[n,64] = X[n,Kd] @ W[Kd,64] ----------
template<int Kd>
__global__ void __launch_bounds__(256) gemm_tile(const float* __restrict__ X,
                                                 const float* __restrict__ W,
                                                 float* __restrict__ out, int n) {
    __shared__ float sW[Kd * 64];
    const int tid = threadIdx.x;
    for (int t = tid; t < Kd * 16; t += 256)
        ((float4*)sW)[t] = ((const float4*)W)[t];
    __syncthreads();

    const int cq = tid >> 6;
    const int rg = tid & 63;
    const int row0 = blockIdx.x * 256 + rg * 4;
    const float4* sW4 = (const float4*)sW;

    float4 acc[4][4];
    #pragma unroll
    for (int r = 0; r < 4; ++r)
        #pragma unroll
        for (int c = 0; c < 4; ++c) acc[r][c] = make_float4(0.f, 0.f, 0.f, 0.f);

    int rl[4];
    #pragma unroll
    for (int r = 0; r < 4; ++r) {
        int rr = row0 + r;
        rl[r] = rr < n ? rr : (n - 1);
    }

    for (int k0 = 0; k0 < Kd; k0 += 8) {
        float4 xa[4][2];
        #pragma unroll
        for (int r = 0; r < 4; ++r) {
            const float4* xp = (const float4*)(X + (size_t)rl[r] * Kd + k0);
            xa[r][0] = xp[0];
            xa[r][1] = xp[1];
        }
        #pragma unroll
        for (int kk = 0; kk < 8; ++kk) {
            float xk[4];
            #pragma unroll
            for (int r = 0; r < 4; ++r) {
                float4 h = xa[r][kk >> 2];
                xk[r] = (kk & 3) == 0 ? h.x : (kk & 3) == 1 ? h.y : (kk & 3) == 2 ? h.z : h.w;
            }
            #pragma unroll
            for (int c = 0; c < 4; ++c) {
                float4 w4 = sW4[(k0 + kk) * 16 + cq * 4 + c];
                #pragma unroll
                for (int r = 0; r < 4; ++r) {
                    acc[r][c].x += xk[r] * w4.x;
                    acc[r][c].y += xk[r] * w4.y;
                    acc[r][c].z += xk[r] * w4.z;
                    acc[r][c].w += xk[r] * w4.w;
                }
            }
        }
    }

    #pragma unroll
    for (int r = 0; r < 4; ++r) {
        int rr = row0 + r;
        if (rr < n) {
            float4* op = (float4*)(out + (size_t)rr * 64 + cq * 16);
            #pragma unroll
            for (int c = 0; c < 4; ++c) op[c] = acc[r][c];
        }
    }
}

// -------- fused CSR aggregation (64 feats): one wave per dst row, lane = feat --------
__global__ void __launch_bounds__(256) agg64_fused(const int* __restrict__ rowptr,
                                                   const int* __restrict__ col,
                                                   const float* __restrict__ enormp,
                                                   const float* __restrict__ hpre,
                                                   const float* __restrict__ dinv,
                                                   const float* __restrict__ bias,
                                                   float* __restrict__ hout, int n) {
    int gid = blockIdx.x * 256 + threadIdx.x;
    int row = gid >> 6;
    int lane = gid & 63;
    if (row >= n) return;
    int r0 = rowptr[row], r1 = rowptr[row + 1];
    float acc = 0.0f;
    for (int base = r0; base < r1; base += 64) {
        int e = base + lane;
        int cv = 0; float ev = 0.0f;
        if (e < r1) { cv = col[e]; ev = enormp[e]; }
        int m = r1 - base; if (m > 64) m = 64;
        int j = 0;
        for (; j + 8 <= m; j += 8) {
            int   s0 = __shfl(cv, j, 64),     s1 = __shfl(cv, j + 1, 64);
            int   s2 = __shfl(cv, j + 2, 64), s3 = __shfl(cv, j + 3, 64);
            int   s4 = __shfl(cv, j + 4, 64), s5 = __shfl(cv, j + 5, 64);
            int   s6 = __shfl(cv, j + 6, 64), s7 = __shfl(cv, j + 7, 64);
            float c0 = __shfl(ev, j, 64),     c1 = __shfl(ev, j + 1, 64);
            float c2 = __shfl(ev, j + 2, 64), c3 = __shfl(ev, j + 3, 64);
            float c4 = __shfl(ev, j + 4, 64), c5 = __shfl(ev, j + 5, 64);
            float c6 = __shfl(ev, j + 6, 64), c7 = __shfl(ev, j + 7, 64);
            float v0 = hpre[(size_t)s0 * 64 + lane];
            float v1 = hpre[(size_t)s1 * 64 + lane];
            float v2 = hpre[(size_t)s2 * 64 + lane];
            float v3 = hpre[(size_t)s3 * 64 + lane];
            float v4 = hpre[(size_t)s4 * 64 + lane];
            float v5 = hpre[(size_t)s5 * 64 + lane];
            float v6 = hpre[(size_t)s6 * 64 + lane];
            float v7 = hpre[(size_t)s7 * 64 + lane];
            acc += c0 * v0; acc += c1 * v1; acc += c2 * v2; acc += c3 * v3;
            acc += c4 * v4; acc += c5 * v5; acc += c6 * v6; acc += c7 * v7;
        }
        for (; j + 4 <= m; j += 4) {
            int   s0 = __shfl(cv, j, 64),     s1 = __shfl(cv, j + 1, 64);
            int   s2 = __shfl(cv, j + 2, 64), s3 = __shfl(cv, j + 3, 64);
            float c0 = __shfl(ev, j, 64),     c1 = __shfl(ev, j + 1, 64);
            float c2 = __shfl(ev, j + 2, 64), c3 = __shfl(ev, j + 3, 64);
            float v0 = hpre[(size_t)s0 * 64 + lane];
            float v1 = hpre[(size_t)s1 * 64 + lane];
            float v2 = hpre[(size_t)s2 * 64 + lane];
            float v3 = hpre[(size_t)s3 * 64 + lane];
            acc += c0 * v0; acc += c1 * v1; acc += c2 * v2; acc += c3 * v3;
        }
        for (; j < m; ++j) {
            int s = __shfl(cv, j, 64);
            float coef = __shfl(ev, j, 64);
            acc += coef * hpre[(size_t)s * 64 + lane];
        }
    }
    float dv = dinv[row];
    hout[gid] = tanhf(acc + dv * dv * hpre[(size_t)row * 64 + lane] + bias[lane]);
}

// ---------------- h2 @ W2 (64 -> 1), one wave per row ----------------
__global__ void gemv64(const float* __restrict__ h, const float* __restrict__ w,
                       float* __restrict__ out, int n) {
    int gid = blockIdx.x * blockDim.x + threadIdx.x;
    int row = gid >> 6;
    int lane = gid & 63;
    if (row >= n) return;
    float v = h[(size_t)row * 64 + lane] * w[lane];
    for (int off = 32; off > 0; off >>= 1) v += __shfl_down(v, off, 64);
    if (lane == 0) out[row] = v;
}

// -------- fused CSR aggregation (1 feat): one thread per dst row --------
__global__ void agg1_fused(const int* __restrict__ rowptr, const int* __restrict__ col,
                           const float* __restrict__ enormp, const float* __restrict__ hpre3,
                           const float* __restrict__ dinv, const float* __restrict__ b2,
                           float* __restrict__ h3, int n) {
    int i = blockIdx.x * blockDim.x + threadIdx.x;
    if (i >= n) return;
    float acc = 0.0f;
    int r1 = rowptr[i + 1];
    for (int e = rowptr[i]; e < r1; ++e) acc += enormp[e] * hpre3[col[e]];
    float dv = dinv[i];
    h3[i] = tanhf(acc + dv * dv * hpre3[i] + b2[0]);
}

// ---------------- group compaction: deterministic counting sort ----------------
__global__ void __launch_bounds__(256) grp_hist(const int* __restrict__ group,
                                                int* __restrict__ bcnt, int n) {
    __shared__ int lh[NG];
    int b = blockIdx.x, t = threadIdx.x;
    if (t < NG) lh[t] = 0;
    __syncthreads();
    int i = b * 256 + t;
    if (i < n) atomicAdd(&lh[group[i]], 1);
    __syncthreads();
    if (t < NG) bcnt[t * NBLK + b] = lh[t];
}

__global__ void __launch_bounds__(512) grp_scan(const int* __restrict__ bcnt,
                                                int* __restrict__ boff,
                                                int* __restrict__ cnt) {
    __shared__ int s[512];
    int g = blockIdx.x, t = threadIdx.x;
    int orig = t < NBLK ? bcnt[g * NBLK + t] : 0;
    s[t] = orig;
    __syncthreads();
    for (int o = 1; o < 512; o <<= 1) {
        int v = t >= o ? s[t - o] : 0;
        __syncthreads();
        s[t] += v;
        __syncthreads();
    }
    if (t < NBLK) boff[g * NBLK + t] = s[t] - orig;
    if (t == 511) cnt[g] = s[NBLK - 1] > CAP ? CAP : s[NBLK - 1];
}

__global__ void __launch_bounds__(256) grp_fill(const int* __restrict__ group,
                                                const int* __restrict__ boff,
                                                int* __restrict__ lists, int n) {
    __shared__ int lcur[NG];
    int b = blockIdx.x, t = threadIdx.x;
    if (t < NG) lcur[t] = 0;
    __syncthreads();
    int i = b * 256 + t;
    if (i < n) {
        int g = group[i];
        int p = atomicAdd(&lcur[g], 1);
        int pos = boff[g * NBLK + b] + p;
        if (pos < CAP) lists[g * CAP + pos] = i;
    }
}

// ---------------- per-group top-K by h3: iterative selection in registers ----------
__device__ __forceinline__ unsigned int fkey(float v) {
    unsigned int b = __float_as_uint(v);
    return (b & 0x80000000u) ? ~b : (b | 0x80000000u);
}

__global__ void __launch_bounds__(256) topk_kernel(const int* __restrict__ cnt,
                                                   const int* __restrict__ lists,
                                                   const float* __restrict__ h3,
                                                   int* __restrict__ topk) {
    __shared__ unsigned long long wmax[4];
    __shared__ unsigned long long winner;
    int g = blockIdx.x;
    int tid = threadIdx.x;
    int lane = tid & 63, wid = tid >> 6;
    int c = cnt[g];
    if (c > CAP) c = CAP;

    unsigned long long key[SLOTS];
    #pragma unroll
    for (int s = 0; s < SLOTS; ++s) {
        int e = s * 256 + tid;
        if (e < c) {
            int node = lists[g * CAP + e];
            key[s] = ((unsigned long long)fkey(h3[node]) << 32) | (unsigned int)(~node);
        } else {
            key[s] = 0ull;
        }
    }

    for (int k = 0; k < KTOP; ++k) {
        unsigned long long best = 0ull;
        #pragma unroll
        for (int s = 0; s < SLOTS; ++s) best = key[s] > best ? key[s] : best;
        #pragma unroll
        for (int off = 32; off > 0; off >>= 1) {
            unsigned long long o = __shfl_down(best, off, 64);
            best = o > best ? o : best;
        }
        if (lane == 0) wmax[wid] = best;
        __syncthreads();
        if (tid == 0) {
            unsigned long long b = wmax[0];
            for (int w = 1; w < 4; ++w) b = wmax[w] > b ? wmax[w] : b;
            winner = b;
            topk[g * KTOP + k] = ~(int)(unsigned int)b;
        }
        __syncthreads();
        unsigned long long w = winner;
        #pragma unroll
        for (int s = 0; s < SLOTS; ++s) if (key[s] == w) key[s] = 0ull;
        __syncthreads();
    }
}

// ---------------- fused sort-pool gather + conv1 + maxpool + conv2 ----------------
__global__ void __launch_bounds__(256) pool_conv(const float* __restrict__ h1,
                                                 const float* __restrict__ h2,
                                                 const float* __restrict__ h3,
                                                 const int* __restrict__ topk,
                                                 const float* __restrict__ c1w,
                                                 const float* __restrict__ c1b,
                                                 const float* __restrict__ c2w,
                                                 const float* __restrict__ c2b,
                                                 float* __restrict__ out) {
    __shared__ float sfeat[KTOP * DFLAT];
    __shared__ float sy[NC1 * KTOP];
    __shared__ float sm[NC1 * (KTOP / 2)];
    int g = blockIdx.x;
    int tid = threadIdx.x;

    for (int t = tid; t < KTOP * DFLAT; t += blockDim.x) {
        int k = t / DFLAT, d = t - k * DFLAT;
        int node = topk[g * KTOP + k];
        float v;
        if (d < 64)        v = h1[(size_t)node * 64 + d];
        else if (d < 128)  v = h2[(size_t)node * 64 + (d - 64)];
        else               v = h3[node];
        sfeat[t] = v;
    }
    __syncthreads();

    for (int t = tid; t < NC1 * KTOP; t += blockDim.x) {
        int c = t / KTOP, k = t - c * KTOP;
        float acc = c1b[c];
        const float* w = c1w + c * DFLAT;
        const float* f = sfeat + k * DFLAT;
        for (int d = 0; d < DFLAT; ++d) acc += f[d] * w[d];
        sy[c * KTOP + k] = fmaxf(acc, 0.0f);
    }
    __syncthreads();

    for (int t = tid; t < NC1 * (KTOP / 2); t += blockDim.x) {
        int c = t / (KTOP / 2), j = t - c * (KTOP / 2);
        sm[t] = fmaxf(sy[c * KTOP + 2 * j], sy[c * KTOP + 2 * j + 1]);
    }
    __syncthreads();

    for (int t = tid; t < NC2 * TOUT; t += blockDim.x) {
        int c2 = t / TOUT, tt = t - c2 * TOUT;
        float acc = c2b[c2];
        for (int c1i = 0; c1i < NC1; ++c1i) {
            const float* w = c2w + (c2 * NC1 + c1i) * KSZ;
            const float* m = sm + c1i * (KTOP / 2) + tt;
            for (int s = 0; s < KSZ; ++s) acc += m[s] * w[s];
        }
        out[g * NC2 * TOUT + t] += fmaxf(acc, 0.0f);
    }
}

// ---------------- host ----------------
static inline size_t align256(size_t x) { return (x + 255) & ~(size_t)255; }

extern "C" void kernel_launch(void* const* d_in, const int* in_sizes, int n_in,
                              void* d_out, int out_size, void* d_ws, size_t ws_size,
                              hipStream_t stream) {
    const float* x       = (const float*)d_in[0];
    const int*   eidx    = (const int*)d_in[1];    // [R,2,E]
    const float* ew      = (const float*)d_in[2];  // [R,E]
    const int*   group   = (const int*)d_in[3];    // [N]
    const float* W0      = (const float*)d_in[4];  // [R,128,64]
    const float* b0      = (const float*)d_in[5];
    const float* W1      = (const float*)d_in[6];  // [R,64,64]
    const float* b1      = (const float*)d_in[7];
    const float* W2      = (const float*)d_in[8];  // [R,64,1]
    const float* b2      = (const float*)d_in[9];
    const float* c1w     = (const float*)d_in[10];
    const float* c1b     = (const float*)d_in[11];
    const float* c2w     = (const float*)d_in[12];
    const float* c2b     = (const float*)d_in[13];
    float* out = (float*)d_out;

    char* ws = (char*)d_ws;
    size_t off = 0;
    float* dinv    = (float*)(ws + off); off = align256(off + (size_t)N_NODES * 4);
    int*   rowptr  = (int*)(ws + off);   off = align256(off + (size_t)(N_NODES + 1) * 4);
    int*   ccnt    = (int*)(ws + off);   off = align256(off + (size_t)N_NODES * 4);
    int*   bsum    = (int*)(ws + off);   off = align256(off + (size_t)512 * 4);
    int*   col     = (int*)(ws + off);   off = align256(off + (size_t)E_EDGES * 4);
    float* ewp     = (float*)(ws + off); off = align256(off + (size_t)E_EDGES * 4);
    int*   eorig   = (int*)(ws + off);   off = align256(off + (size_t)E_EDGES * 4);
    float* enormp  = (float*)(ws + off); off = align256(off + (size_t)E_EDGES * 4);
    float* hpre    = (float*)(ws + off); off = align256(off + (size_t)N_NODES * 64 * 4);
    float* h1      = (float*)(ws + off); off = align256(off + (size_t)N_NODES * 64 * 4);
    float* h2      = (float*)(ws + off); off = align256(off + (size_t)N_NODES * 64 * 4);
    float* hpre3   = (float*)(ws + off); off = align256(off + (size_t)N_NODES * 4);
    float* h3      = (float*)(ws + off); off = align256(off + (size_t)N_NODES * 4);
    int*   cnt     = (int*)(ws + off);   off = align256(off + (size_t)NG * 4);
    int*   lists   = (int*)(ws + off);   off = align256(off + (size_t)NG * CAP * 4);
    int*   topk    = (int*)(ws + off);   off = align256(off + (size_t)NG * KTOP * 4);
    int*   bcnt    = (int*)(ws + off);   off = align256(off + (size_t)NG * NBLK * 4);
    int*   boff    = (int*)(ws + off);   off = align256(off + (size_t)NG * NBLK * 4);
    int*   bcur    = (int*)(ws + off);   off = align256(off + (size_t)NB * 4);
    int4*  staged  = (int4*)(ws + off);  off = align256(off + (size_t)E_EDGES * 16);
    (void)ws_size;

    const int B = 256;
    const int nOut = NG * NC2 * TOUT;
    const int gN   = (N_NODES + B - 1) / B;           // 391
    const int gE   = (E_EDGES + B - 1) / B;           // 6250
    const int gW   = (N_NODES * 64 + B - 1) / B;      // 25000
    const int gT   = (N_NODES + 255) / 256;           // gemm_tile

    zero_f32<<<(nOut + B - 1) / B, B, 0, stream>>>(out, nOut);

    // group compaction: deterministic counting sort, once per launch
    grp_hist<<<NBLK, B, 0, stream>>>(group, bcnt, N_NODES);
    grp_scan<<<NG, 512, 0, stream>>>(bcnt, boff, cnt);
    grp_fill<<<NBLK, B, 0, stream>>>(group, boff, lists, N_NODES);

    for (int r = 0; r < R_REL; ++r) {
        const int* src = eidx + (size_t)r * 2 * E_EDGES;
        const int* dst = src + E_EDGES;
        const float* ewr = ew + (size_t)r * E_EDGES;

        // ---- rowptr ----
        zero_i32<<<gN, B, 0, stream>>>(ccnt, N_NODES);
        hist_kernel<<<gE, B, 0, stream>>>(dst, ccnt, E_EDGES);
        block_sum<<<gN, B, 0, stream>>>(ccnt, bsum, N_NODES);
        scan_bsum<<<1, 512, 0, stream>>>(bsum, gN);
        scan_blocks<<<gN, B, 0, stream>>>(ccnt, bsum, rowptr, N_NODES);

        // ---- binned permutation build (chunked stage, rowptr-based bases) ----
        zero_i32<<<2, B, 0, stream>>>(bcur, NB);
        bin_stage<<<NCHUNK, B, 0, stream>>>(dst, src, ewr, rowptr, bcur, staged, E_EDGES);
        bin_scatter<<<NB, B, 0, stream>>>(staged, rowptr, col, ewp, eorig, N_NODES);
        sort_rows<<<gN, B, 0, stream>>>(rowptr, col, ewp, eorig, N_NODES);
        deg_dinv<<<gN, B, 0, stream>>>(rowptr, ewp, dinv, N_NODES);
        enorm_csr<<<gN, B, 0, stream>>>(rowptr, col, ewp, dinv, enormp, N_NODES);

        // layer 1
        gemm_tile<128><<<gT, B, 0, stream>>>(x, W0 + (size_t)r * 128 * 64, hpre, N_NODES);
        agg64_fused<<<gW, B, 0, stream>>>(rowptr, col, enormp, hpre, dinv,
                                          b0 + (size_t)r * 64, h1, N_NODES);
        // layer 2
        gemm_tile<64><<<gT, B, 0, stream>>>(h1, W1 + (size_t)r * 64 * 64, hpre, N_NODES);
        agg64_fused<<<gW, B, 0, stream>>>(rowptr, col, enormp, hpre, dinv,
                                          b1 + (size_t)r * 64, h2, N_NODES);
        // layer 3
        gemv64<<<gW, B, 0, stream>>>(h2, W2 + (size_t)r * 64, hpre3, N_NODES);
        agg1_fused<<<gN, B, 0, stream>>>(rowptr, col, enormp, hpre3, dinv, b2 + r, h3, N_NODES);

        // sort pooling + convs
        topk_kernel<<<NG, B, 0, stream>>>(cnt, lists, h3, topk);
        pool_conv<<<NG, B, 0, stream>>>(h1, h2, h3, topk, c1w, c1b, c2w, c2b, out);
    }
}

// Round 10
// 1639.354 us; speedup vs baseline: 1.2837x; 1.2814x over previous
//
#include <hip/hip_runtime.h>
#include <math.h>

#define N_NODES 100000
#define R_REL   3
#define E_EDGES 1600000
#define HID     64
#define DFLAT   129
#define KTOP    30
#define NC1     16
#define NC2     32
#define KSZ     5
#define NG      64
#define CAP     2048
#define SLOTS   8     // CAP / 256
#define TOUT    11    // K/2 - KS + 1
#define NBLK    391   // ceil(N_NODES/256)
#define NB      391   // coarse buckets (dst>>8)
#define NCHUNK  512   // bin_stage blocks
#define CHSZ    3125  // E_EDGES / NCHUNK (exact)

// ---------------- utility ----------------
__global__ void zero_f32(float* p, int n) {
    int i = blockIdx.x * blockDim.x + threadIdx.x;
    int stride = gridDim.x * blockDim.x;
    for (; i < n; i += stride) p[i] = 0.0f;
}

__global__ void zero_i32(int* p, int n) {
    int i = blockIdx.x * blockDim.x + threadIdx.x;
    if (i < n) p[i] = 0;
}

// ---------------- CSR rowptr build ----------------
__global__ void hist_kernel(const int* __restrict__ dst, int* __restrict__ cnt, int e) {
    int i = blockIdx.x * blockDim.x + threadIdx.x;
    if (i < e) atomicAdd(&cnt[dst[i]], 1);
}

__global__ void block_sum(const int* __restrict__ cnt, int* __restrict__ bsum, int n) {
    __shared__ int s[256];
    int i = blockIdx.x * 256 + threadIdx.x;
    s[threadIdx.x] = i < n ? cnt[i] : 0;
    __syncthreads();
    for (int o = 128; o > 0; o >>= 1) {
        if (threadIdx.x < o) s[threadIdx.x] += s[threadIdx.x + o];
        __syncthreads();
    }
    if (threadIdx.x == 0) bsum[blockIdx.x] = s[0];
}

__global__ void __launch_bounds__(512) scan_bsum(int* bsum, int nb) {
    __shared__ int s[512];
    int t = threadIdx.x;
    int orig = t < nb ? bsum[t] : 0;
    s[t] = orig;
    __syncthreads();
    for (int o = 1; o < 512; o <<= 1) {
        int v = t >= o ? s[t - o] : 0;
        __syncthreads();
        s[t] += v;
        __syncthreads();
    }
    if (t < nb) bsum[t] = s[t] - orig;   // exclusive
}

__global__ void scan_blocks(const int* __restrict__ cnt, const int* __restrict__ boff,
                            int* __restrict__ rowptr, int n) {
    __shared__ int s[256];
    int b = blockIdx.x, t = threadIdx.x;
    int i = b * 256 + t;
    s[t] = i < n ? cnt[i] : 0;
    __syncthreads();
    for (int o = 1; o < 256; o <<= 1) {
        int u = t >= o ? s[t - o] : 0;
        __syncthreads();
        s[t] += u;
        __syncthreads();
    }
    if (i < n) rowptr[i + 1] = s[t] + boff[b];
    if (i == 0) rowptr[0] = 0;
}

// ---------------- binned permutation build (deterministic chunk order) -------
// per-chunk bucket histogram
__global__ void __launch_bounds__(256) bin_hist(const int* __restrict__ dst,
                                                int* __restrict__ chist, int e) {
    __shared__ int hist[NB];
    int t = threadIdx.x, c = blockIdx.x;
    int e0 = c * CHSZ;
    int e1 = e0 + CHSZ; if (e1 > e) e1 = e;
    for (int j = t; j < NB; j += 256) hist[j] = 0;
    __syncthreads();
    for (int i = e0 + t; i < e1; i += 256)
        atomicAdd(&hist[dst[i] >> 8], 1);
    __syncthreads();
    for (int j = t; j < NB; j += 256) chist[j * NCHUNK + c] = hist[j];
}

// per-bucket exclusive scan over chunks -> deterministic chunk offsets
__global__ void __launch_bounds__(512) bin_scan(const int* __restrict__ chist,
                                                const int* __restrict__ rowptr,
                                                int* __restrict__ chunkoff) {
    __shared__ int s[512];
    int b = blockIdx.x, t = threadIdx.x;
    int orig = t < NCHUNK ? chist[b * NCHUNK + t] : 0;
    s[t] = orig;
    __syncthreads();
    for (int o = 1; o < 512; o <<= 1) {
        int v = t >= o ? s[t - o] : 0;
        __syncthreads();
        s[t] += v;
        __syncthreads();
    }
    if (t < NCHUNK) chunkoff[b * NCHUNK + t] = rowptr[b << 8] + s[t] - orig;
}

// stage edges into bucket regions at precomputed (chunk-ordered) offsets.
// Within-bucket order = chunk order ~= edge order; small within-chunk scrambles
// are corrected by sort_rows.
__global__ void __launch_bounds__(256) bin_stage(const int* __restrict__ dst,
                                                 const int* __restrict__ src,
                                                 const float* __restrict__ ew,
                                                 const int* __restrict__ chunkoff,
                                                 int4* __restrict__ staged, int e) {
    __shared__ int base[NB];
    __shared__ int lcur[NB];
    int t = threadIdx.x, c = blockIdx.x;
    int e0 = c * CHSZ;
    int e1 = e0 + CHSZ; if (e1 > e) e1 = e;
    for (int j = t; j < NB; j += 256) {
        base[j] = chunkoff[j * NCHUNK + c];
        lcur[j] = 0;
    }
    __syncthreads();
    for (int i = e0 + t; i < e1; i += 256) {
        int d = dst[i];
        int bin = d >> 8;
        int r = atomicAdd(&lcur[bin], 1);
        staged[(size_t)(base[bin] + r)] = make_int4(d, i, src[i], __float_as_int(ew[i]));
    }
}

// one block per bucket; per-dst cursors in LDS; final writes land in a ~48 KB
// window per bucket (cacheline-resident). Processes staged in batch order, so
// near-sortedness is preserved.
__global__ void __launch_bounds__(256) bin_scatter(const int4* __restrict__ staged,
                                                   const int* __restrict__ rowptr,
                                                   int* __restrict__ col,
                                                   float* __restrict__ ewp,
                                                   int* __restrict__ eorig, int n) {
    __shared__ int cur[256];
    int b = blockIdx.x, t = threadIdx.x;
    int node = b * 256 + t;
    cur[t] = (node < n) ? rowptr[node] : 0;
    __syncthreads();
    int s0 = rowptr[b << 8];
    int nend = (b + 1) << 8; if (nend > n) nend = n;
    int s1 = rowptr[nend];
    for (int i = s0 + t; i < s1; i += 256) {
        int4 v = staged[(size_t)i];
        int p = atomicAdd(&cur[v.x & 255], 1);
        col[p] = v.z;
        ewp[p] = __int_as_float(v.w);
        eorig[p] = v.y;
    }
}

// stable order: sort each row's slots by original edge index (input is nearly
// sorted -> insertion sort ~O(d)). Guarantees numpy edge-order accumulation.
__global__ void sort_rows(const int* __restrict__ rowptr, int* __restrict__ col,
                          float* __restrict__ ewp, int* __restrict__ eorig, int n) {
    int i = blockIdx.x * blockDim.x + threadIdx.x;
    if (i >= n) return;
    int r0 = rowptr[i], r1 = rowptr[i + 1];
    for (int a = r0 + 1; a < r1; ++a) {
        int ke = eorig[a]; int kc = col[a]; float kw = ewp[a];
        int b = a - 1;
        while (b >= r0 && eorig[b] > ke) {
            eorig[b + 1] = eorig[b]; col[b + 1] = col[b]; ewp[b + 1] = ewp[b];
            --b;
        }
        eorig[b + 1] = ke; col[b + 1] = kc; ewp[b + 1] = kw;
    }
}

__global__ void deg_dinv(const int* __restrict__ rowptr, const float* __restrict__ ewp,
                         float* __restrict__ dinv, int n) {
    int i = blockIdx.x * blockDim.x + threadIdx.x;
    if (i < n) {
        float s = 0.0f;
        int r1 = rowptr[i + 1];
        for (int e = rowptr[i]; e < r1; ++e) s += ewp[e];
        dinv[i] = 1.0f / sqrtf(s + 1.0f);
    }
}

__global__ void enorm_csr(const int* __restrict__ rowptr, const int* __restrict__ col,
                          const float* __restrict__ ewp, const float* __restrict__ dinv,
                          float* __restrict__ enormp, int n) {
    int i = blockIdx.x * blockDim.x + threadIdx.x;
    if (i < n) {
        float di = dinv[i];
        int r1 = rowptr[i + 1];
        for (int e = rowptr[i]; e < r1; ++e)
            enormp[e] = dinv[col[e]] * ewp[e] * di;
    }
}

// ---------------- register-tiled GEMM: out[n,64] = X[n,Kd] @ W[Kd,64] ----------
template<int Kd>
__global__ void __launch_bounds__(256) gemm_tile(const float* __restrict__ X,
                                                 const float* __restrict__ W,
                                                 float* __restrict__ out, int n) {
    __shared__ float sW[Kd * 64];
    const int tid = threadIdx.x;
    for (int t = tid; t < Kd * 16; t += 256)
        ((float4*)sW)[t] = ((const float4*)W)[t];
    __syncthreads();

    const int cq = tid >> 6;
    const int rg = tid & 63;
    const int row0 = blockIdx.x * 256 + rg * 4;
    const float4* sW4 = (const float4*)sW;

    float4 acc[4][4];
    #pragma unroll
    for (int r = 0; r < 4; ++r)
        #pragma unroll
        for (int c = 0; c < 4; ++c) acc[r][c] = make_float4(0.f, 0.f, 0.f, 0.f);

    int rl[4];
    #pragma unroll
    for (int r = 0; r < 4; ++r) {
        int rr = row0 + r;
        rl[r] = rr < n ? rr : (n - 1);
    }

    for (int k0 = 0; k0 < Kd; k0 += 8) {
        float4 xa[4][2];
        #pragma unroll
        for (int r = 0; r < 4; ++r) {
            const float4* xp = (const float4*)(X + (size_t)rl[r] * Kd + k0);
            xa[r][0] = xp[0];
            xa[r][1] = xp[1];
        }
        #pragma unroll
        for (int kk = 0; kk < 8; ++kk) {
            float xk[4];
            #pragma unroll
            for (int r = 0; r < 4; ++r) {
                float4 h = xa[r][kk >> 2];
                xk[r] = (kk & 3) == 0 ? h.x : (kk & 3) == 1 ? h.y : (kk & 3) == 2 ? h.z : h.w;
            }
            #pragma unroll
            for (int c = 0; c < 4; ++c) {
                float4 w4 = sW4[(k0 + kk) * 16 + cq * 4 + c];
                #pragma unroll
                for (int r = 0; r < 4; ++r) {
                    acc[r][c].x += xk[r] * w4.x;
                    acc[r][c].y += xk[r] * w4.y;
                    acc[r][c].z += xk[r] * w4.z;
                    acc[r][c].w += xk[r] * w4.w;
                }
            }
        }
    }

    #pragma unroll
    for (int r = 0; r < 4; ++r) {
        int rr = row0 + r;
        if (rr < n) {
            float4* op = (float4*)(out + (size_t)rr * 64 + cq * 16);
            #pragma unroll
            for (int c = 0; c < 4; ++c) op[c] = acc[r][c];
        }
    }
}

// -------- fused CSR aggregation (64 feats): one wave per dst row, lane = feat --------
__global__ void __launch_bounds__(256) agg64_fused(const int* __restrict__ rowptr,
                                                   const int* __restrict__ col,
                                                   const float* __restrict__ enormp,
                                                   const float* __restrict__ hpre,
                                                   const float* __restrict__ dinv,
                                                   const float* __restrict__ bias,
                                                   float* __restrict__ hout, int n) {
    int gid = blockIdx.x * 256 + threadIdx.x;
    int row = gid >> 6;
    int lane = gid & 63;
    if (row >= n) return;
    int r0 = rowptr[row], r1 = rowptr[row + 1];
    float acc = 0.0f;
    for (int base = r0; base < r1; base += 64) {
        int e = base + lane;
        int cv = 0; float ev = 0.0f;
        if (e < r1) { cv = col[e]; ev = enormp[e]; }
        int m = r1 - base; if (m > 64) m = 64;
        int j = 0;
        for (; j + 8 <= m; j += 8) {
            int   s0 = __shfl(cv, j, 64),     s1 = __shfl(cv, j + 1, 64);
            int   s2 = __shfl(cv, j + 2, 64), s3 = __shfl(cv, j + 3, 64);
            int   s4 = __shfl(cv, j + 4, 64), s5 = __shfl(cv, j + 5, 64);
            int   s6 = __shfl(cv, j + 6, 64), s7 = __shfl(cv, j + 7, 64);
            float c0 = __shfl(ev, j, 64),     c1 = __shfl(ev, j + 1, 64);
            float c2 = __shfl(ev, j + 2, 64), c3 = __shfl(ev, j + 3, 64);
            float c4 = __shfl(ev, j + 4, 64), c5 = __shfl(ev, j + 5, 64);
            float c6 = __shfl(ev, j + 6, 64), c7 = __shfl(ev, j + 7, 64);
            float v0 = hpre[(size_t)s0 * 64 + lane];
            float v1 = hpre[(size_t)s1 * 64 + lane];
            float v2 = hpre[(size_t)s2 * 64 + lane];
            float v3 = hpre[(size_t)s3 * 64 + lane];
            float v4 = hpre[(size_t)s4 * 64 + lane];
            float v5 = hpre[(size_t)s5 * 64 + lane];
            float v6 = hpre[(size_t)s6 * 64 + lane];
            float v7 = hpre[(size_t)s7 * 64 + lane];
            acc += c0 * v0; acc += c1 * v1; acc += c2 * v2; acc += c3 * v3;
            acc += c4 * v4; acc += c5 * v5; acc += c6 * v6; acc += c7 * v7;
        }
        for (; j + 4 <= m; j += 4) {
            int   s0 = __shfl(cv, j, 64),     s1 = __shfl(cv, j + 1, 64);
            int   s2 = __shfl(cv, j + 2, 64), s3 = __shfl(cv, j + 3, 64);
            float c0 = __shfl(ev, j, 64),     c1 = __shfl(ev, j + 1, 64);
            float c2 = __shfl(ev, j + 2, 64), c3 = __shfl(ev, j + 3, 64);
            float v0 = hpre[(size_t)s0 * 64 + lane];
            float v1 = hpre[(size_t)s1 * 64 + lane];
            float v2 = hpre[(size_t)s2 * 64 + lane];
            float v3 = hpre[(size_t)s3 * 64 + lane];
            acc += c0 * v0; acc += c1 * v1; acc += c2 * v2; acc += c3 * v3;
        }
        for (; j < m; ++j) {
            int s = __shfl(cv, j, 64);
            float coef = __shfl(ev, j, 64);
            acc += coef * hpre[(size_t)s * 64 + lane];
        }
    }
    float dv = dinv[row];
    hout[gid] = tanhf(acc + dv * dv * hpre[(size_t)row * 64 + lane] + bias[lane]);
}

// ---------------- h2 @ W2 (64 -> 1), one wave per row ----------------
__global__ void gemv64(const float* __restrict__ h, const float* __restrict__ w,
                       float* __restrict__ out, int n) {
    int gid = blockIdx.x * blockDim.x + threadIdx.x;
    int row = gid >> 6;
    int lane = gid & 63;
    if (row >= n) return;
    float v = h[(size_t)row * 64 + lane] * w[lane];
    for (int off = 32; off > 0; off >>= 1) v += __shfl_down(v, off, 64);
    if (lane == 0) out[row] = v;
}

// -------- fused CSR aggregation (1 feat): one thread per dst row --------
__global__ void agg1_fused(const int* __restrict__ rowptr, const int* __restrict__ col,
                           const float* __restrict__ enormp, const float* __restrict__ hpre3,
                           const float* __restrict__ dinv, const float* __restrict__ b2,
                           float* __restrict__ h3, int n) {
    int i = blockIdx.x * blockDim.x + threadIdx.x;
    if (i >= n) return;
    float acc = 0.0f;
    int r1 = rowptr[i + 1];
    for (int e = rowptr[i]; e < r1; ++e) acc += enormp[e] * hpre3[col[e]];
    float dv = dinv[i];
    h3[i] = tanhf(acc + dv * dv * hpre3[i] + b2[0]);
}

// ---------------- group compaction: deterministic counting sort ----------------
__global__ void __launch_bounds__(256) grp_hist(const int* __restrict__ group,
                                                int* __restrict__ bcnt, int n) {
    __shared__ int lh[NG];
    int b = blockIdx.x, t = threadIdx.x;
    if (t < NG) lh[t] = 0;
    __syncthreads();
    int i = b * 256 + t;
    if (i < n) atomicAdd(&lh[group[i]], 1);
    __syncthreads();
    if (t < NG) bcnt[t * NBLK + b] = lh[t];
}

__global__ void __launch_bounds__(512) grp_scan(const int* __restrict__ bcnt,
                                                int* __restrict__ boff,
                                                int* __restrict__ cnt) {
    __shared__ int s[512];
    int g = blockIdx.x, t = threadIdx.x;
    int orig = t < NBLK ? bcnt[g * NBLK + t] : 0;
    s[t] = orig;
    __syncthreads();
    for (int o = 1; o < 512; o <<= 1) {
        int v = t >= o ? s[t - o] : 0;
        __syncthreads();
        s[t] += v;
        __syncthreads();
    }
    if (t < NBLK) boff[g * NBLK + t] = s[t] - orig;
    if (t == 511) cnt[g] = s[NBLK - 1] > CAP ? CAP : s[NBLK - 1];
}

__global__ void __launch_bounds__(256) grp_fill(const int* __restrict__ group,
                                                const int* __restrict__ boff,
                                                int* __restrict__ lists, int n) {
    __shared__ int lcur[NG];
    int b = blockIdx.x, t = threadIdx.x;
    if (t < NG) lcur[t] = 0;
    __syncthreads();
    int i = b * 256 + t;
    if (i < n) {
        int g = group[i];
        int p = atomicAdd(&lcur[g], 1);
        int pos = boff[g * NBLK + b] + p;
        if (pos < CAP) lists[g * CAP + pos] = i;
    }
}

// ---------------- per-group top-K by h3: iterative selection in registers ----------
__device__ __forceinline__ unsigned int fkey(float v) {
    unsigned int b = __float_as_uint(v);
    return (b & 0x80000000u) ? ~b : (b | 0x80000000u);
}

__global__ void __launch_bounds__(256) topk_kernel(const int* __restrict__ cnt,
                                                   const int* __restrict__ lists,
                                                   const float* __restrict__ h3,
                                                   int* __restrict__ topk) {
    __shared__ unsigned long long wmax[4];
    __shared__ unsigned long long winner;
    int g = blockIdx.x;
    int tid = threadIdx.x;
    int lane = tid & 63, wid = tid >> 6;
    int c = cnt[g];
    if (c > CAP) c = CAP;

    unsigned long long key[SLOTS];
    #pragma unroll
    for (int s = 0; s < SLOTS; ++s) {
        int e = s * 256 + tid;
        if (e < c) {
            int node = lists[g * CAP + e];
            key[s] = ((unsigned long long)fkey(h3[node]) << 32) | (unsigned int)(~node);
        } else {
            key[s] = 0ull;
        }
    }

    for (int k = 0; k < KTOP; ++k) {
        unsigned long long best = 0ull;
        #pragma unroll
        for (int s = 0; s < SLOTS; ++s) best = key[s] > best ? key[s] : best;
        #pragma unroll
        for (int off = 32; off > 0; off >>= 1) {
            unsigned long long o = __shfl_down(best, off, 64);
            best = o > best ? o : best;
        }
        if (lane == 0) wmax[wid] = best;
        __syncthreads();
        if (tid == 0) {
            unsigned long long b = wmax[0];
            for (int w = 1; w < 4; ++w) b = wmax[w] > b ? wmax[w] : b;
            winner = b;
            topk[g * KTOP + k] = ~(int)(unsigned int)b;
        }
        __syncthreads();
        unsigned long long w = winner;
        #pragma unroll
        for (int s = 0; s < SLOTS; ++s) if (key[s] == w) key[s] = 0ull;
        __syncthreads();
    }
}

// ---------------- fused sort-pool gather + conv1 + maxpool + conv2 ----------------
__global__ void __launch_bounds__(256) pool_conv(const float* __restrict__ h1,
                                                 const float* __restrict__ h2,
                                                 const float* __restrict__ h3,
                                                 const int* __restrict__ topk,
                                                 const float* __restrict__ c1w,
                                                 const float* __restrict__ c1b,
                                                 const float* __restrict__ c2w,
                                                 const float* __restrict__ c2b,
                                                 float* __restrict__ out) {
    __shared__ float sfeat[KTOP * DFLAT];
    __shared__ float sy[NC1 * KTOP];
    __shared__ float sm[NC1 * (KTOP / 2)];
    int g = blockIdx.x;
    int tid = threadIdx.x;

    for (int t = tid; t < KTOP * DFLAT; t += blockDim.x) {
        int k = t / DFLAT, d = t - k * DFLAT;
        int node = topk[g * KTOP + k];
        float v;
        if (d < 64)        v = h1[(size_t)node * 64 + d];
        else if (d < 128)  v = h2[(size_t)node * 64 + (d - 64)];
        else               v = h3[node];
        sfeat[t] = v;
    }
    __syncthreads();

    for (int t = tid; t < NC1 * KTOP; t += blockDim.x) {
        int c = t / KTOP, k = t - c * KTOP;
        float acc = c1b[c];
        const float* w = c1w + c * DFLAT;
        const float* f = sfeat + k * DFLAT;
        for (int d = 0; d < DFLAT; ++d) acc += f[d] * w[d];
        sy[c * KTOP + k] = fmaxf(acc, 0.0f);
    }
    __syncthreads();

    for (int t = tid; t < NC1 * (KTOP / 2); t += blockDim.x) {
        int c = t / (KTOP / 2), j = t - c * (KTOP / 2);
        sm[t] = fmaxf(sy[c * KTOP + 2 * j], sy[c * KTOP + 2 * j + 1]);
    }
    __syncthreads();

    for (int t = tid; t < NC2 * TOUT; t += blockDim.x) {
        int c2 = t / TOUT, tt = t - c2 * TOUT;
        float acc = c2b[c2];
        for (int c1i = 0; c1i < NC1; ++c1i) {
            const float* w = c2w + (c2 * NC1 + c1i) * KSZ;
            const float* m = sm + c1i * (KTOP / 2) + tt;
            for (int s = 0; s < KSZ; ++s) acc += m[s] * w[s];
        }
        out[g * NC2 * TOUT + t] += fmaxf(acc, 0.0f);
    }
}

// ---------------- host ----------------
static inline size_t align256(size_t x) { return (x + 255) & ~(size_t)255; }

extern "C" void kernel_launch(void* const* d_in, const int* in_sizes, int n_in,
                              void* d_out, int out_size, void* d_ws, size_t ws_size,
                              hipStream_t stream) {
    const float* x       = (const float*)d_in[0];
    const int*   eidx    = (const int*)d_in[1];    // [R,2,E]
    const float* ew      = (const float*)d_in[2];  // [R,E]
    const int*   group   = (const int*)d_in[3];    // [N]
    const float* W0      = (const float*)d_in[4];  // [R,128,64]
    const float* b0      = (const float*)d_in[5];
    const float* W1      = (const float*)d_in[6];  // [R,64,64]
    const float* b1      = (const float*)d_in[7];
    const float* W2      = (const float*)d_in[8];  // [R,64,1]
    const float* b2      = (const float*)d_in[9];
    const float* c1w     = (const float*)d_in[10];
    const float* c1b     = (const float*)d_in[11];
    const float* c2w     = (const float*)d_in[12];
    const float* c2b     = (const float*)d_in[13];
    float* out = (float*)d_out;

    char* ws = (char*)d_ws;
    size_t off = 0;
    float* dinv    = (float*)(ws + off); off = align256(off + (size_t)N_NODES * 4);
    int*   rowptr  = (int*)(ws + off);   off = align256(off + (size_t)(N_NODES + 1) * 4);
    int*   ccnt    = (int*)(ws + off);   off = align256(off + (size_t)N_NODES * 4);
    int*   bsum    = (int*)(ws + off);   off = align256(off + (size_t)512 * 4);
    int*   col     = (int*)(ws + off);   off = align256(off + (size_t)E_EDGES * 4);
    float* ewp     = (float*)(ws + off); off = align256(off + (size_t)E_EDGES * 4);
    int*   eorig   = (int*)(ws + off);   off = align256(off + (size_t)E_EDGES * 4);
    float* enormp  = (float*)(ws + off); off = align256(off + (size_t)E_EDGES * 4);
    float* hpre    = (float*)(ws + off); off = align256(off + (size_t)N_NODES * 64 * 4);
    float* h1      = (float*)(ws + off); off = align256(off + (size_t)N_NODES * 64 * 4);
    float* h2      = (float*)(ws + off); off = align256(off + (size_t)N_NODES * 64 * 4);
    float* hpre3   = (float*)(ws + off); off = align256(off + (size_t)N_NODES * 4);
    float* h3      = (float*)(ws + off); off = align256(off + (size_t)N_NODES * 4);
    int*   cnt     = (int*)(ws + off);   off = align256(off + (size_t)NG * 4);
    int*   lists   = (int*)(ws + off);   off = align256(off + (size_t)NG * CAP * 4);
    int*   topk    = (int*)(ws + off);   off = align256(off + (size_t)NG * KTOP * 4);
    int*   bcnt    = (int*)(ws + off);   off = align256(off + (size_t)NG * NBLK * 4);
    int*   boff    = (int*)(ws + off);   off = align256(off + (size_t)NG * NBLK * 4);
    int*   chist   = (int*)(ws + off);   off = align256(off + (size_t)NB * NCHUNK * 4);
    int*   chunkoff= (int*)(ws + off);   off = align256(off + (size_t)NB * NCHUNK * 4);
    int4*  staged  = (int4*)(ws + off);  off = align256(off + (size_t)E_EDGES * 16);
    (void)ws_size;

    const int B = 256;
    const int nOut = NG * NC2 * TOUT;
    const int gN   = (N_NODES + B - 1) / B;           // 391
    const int gE   = (E_EDGES + B - 1) / B;           // 6250
    const int gW   = (N_NODES * 64 + B - 1) / B;      // 25000
    const int gT   = (N_NODES + 255) / 256;           // gemm_tile

    zero_f32<<<(nOut + B - 1) / B, B, 0, stream>>>(out, nOut);

    // group compaction: deterministic counting sort, once per launch
    grp_hist<<<NBLK, B, 0, stream>>>(group, bcnt, N_NODES);
    grp_scan<<<NG, 512, 0, stream>>>(bcnt, boff, cnt);
    grp_fill<<<NBLK, B, 0, stream>>>(group, boff, lists, N_NODES);

    for (int r = 0; r < R_REL; ++r) {
        const int* src = eidx + (size_t)r * 2 * E_EDGES;
        const int* dst = src + E_EDGES;
        const float* ewr = ew + (size_t)r * E_EDGES;

        // ---- rowptr ----
        zero_i32<<<gN, B, 0, stream>>>(ccnt, N_NODES);
        hist_kernel<<<gE, B, 0, stream>>>(dst, ccnt, E_EDGES);
        block_sum<<<gN, B, 0, stream>>>(ccnt, bsum, N_NODES);
        scan_bsum<<<1, 512, 0, stream>>>(bsum, gN);
        scan_blocks<<<gN, B, 0, stream>>>(ccnt, bsum, rowptr, N_NODES);

        // ---- binned permutation build (deterministic chunk order) ----
        bin_hist<<<NCHUNK, B, 0, stream>>>(dst, chist, E_EDGES);
        bin_scan<<<NB, 512, 0, stream>>>(chist, rowptr, chunkoff);
        bin_stage<<<NCHUNK, B, 0, stream>>>(dst, src, ewr, chunkoff, staged, E_EDGES);
        bin_scatter<<<NB, B, 0, stream>>>(staged, rowptr, col, ewp, eorig, N_NODES);
        sort_rows<<<gN, B, 0, stream>>>(rowptr, col, ewp, eorig, N_NODES);
        deg_dinv<<<gN, B, 0, stream>>>(rowptr, ewp, dinv, N_NODES);
        enorm_csr<<<gN, B, 0, stream>>>(rowptr, col, ewp, dinv, enormp, N_NODES);

        // layer 1
        gemm_tile<128><<<gT, B, 0, stream>>>(x, W0 + (size_t)r * 128 * 64, hpre, N_NODES);
        agg64_fused<<<gW, B, 0, stream>>>(rowptr, col, enormp, hpre, dinv,
                                          b0 + (size_t)r * 64, h1, N_NODES);
        // layer 2
        gemm_tile<64><<<gT, B, 0, stream>>>(h1, W1 + (size_t)r * 64 * 64, hpre, N_NODES);
        agg64_fused<<<gW, B, 0, stream>>>(rowptr, col, enormp, hpre, dinv,
                                          b1 + (size_t)r * 64, h2, N_NODES);
        // layer 3
        gemv64<<<gW, B, 0, stream>>>(h2, W2 + (size_t)r * 64, hpre3, N_NODES);
        agg1_fused<<<gN, B, 0, stream>>>(rowptr, col, enormp, hpre3, dinv, b2 + r, h3, N_NODES);

        // sort pooling + convs
        topk_kernel<<<NG, B, 0, stream>>>(cnt, lists, h3, topk);
        pool_conv<<<NG, B, 0, stream>>>(h1, h2, h3, topk, c1w, c1b, c2w, c2b, out);
    }
}

// Round 11
// 1446.333 us; speedup vs baseline: 1.4550x; 1.1335x over previous
//
#include <hip/hip_runtime.h>
#include <math.h>

#define N_NODES 100000
#define R_REL   3
#define E_EDGES 1600000
#define HID     64
#define DFLAT   129
#define KTOP    30
#define NC1     16
#define NC2     32
#define KSZ     5
#define NG      64
#define CAP     2048
#define SLOTS   8     // CAP / 256
#define TOUT    11    // K/2 - KS + 1
#define NBLK    391   // ceil(N_NODES/256)
#define NB      391   // coarse buckets (dst>>8)
#define NCHUNK  512   // bin_stage blocks
#define CHSZ    3125  // E_EDGES / NCHUNK (exact)

// ---------------- utility ----------------
__global__ void zero_f32(float* p, int n) {
    int i = blockIdx.x * blockDim.x + threadIdx.x;
    int stride = gridDim.x * blockDim.x;
    for (; i < n; i += stride) p[i] = 0.0f;
}

// ---------------- binned permutation build (deterministic chunk order) -------
// per-chunk bucket histogram
__global__ void __launch_bounds__(256) bin_hist(const int* __restrict__ dst,
                                                int* __restrict__ chist, int e) {
    __shared__ int hist[NB];
    int t = threadIdx.x, c = blockIdx.x;
    int e0 = c * CHSZ;
    int e1 = e0 + CHSZ; if (e1 > e) e1 = e;
    for (int j = t; j < NB; j += 256) hist[j] = 0;
    __syncthreads();
    for (int i = e0 + t; i < e1; i += 256)
        atomicAdd(&hist[dst[i] >> 8], 1);
    __syncthreads();
    for (int j = t; j < NB; j += 256) chist[j * NCHUNK + c] = hist[j];
}

// per-bucket exclusive scan over chunks (raw, no base) + bucket totals
__global__ void __launch_bounds__(512) bin_scan(const int* __restrict__ chist,
                                                int* __restrict__ chunkoff,
                                                int* __restrict__ btot) {
    __shared__ int s[512];
    int b = blockIdx.x, t = threadIdx.x;
    int orig = t < NCHUNK ? chist[b * NCHUNK + t] : 0;
    s[t] = orig;
    __syncthreads();
    for (int o = 1; o < 512; o <<= 1) {
        int v = t >= o ? s[t - o] : 0;
        __syncthreads();
        s[t] += v;
        __syncthreads();
    }
    if (t < NCHUNK) chunkoff[b * NCHUNK + t] = s[t] - orig;
    if (t == 511) btot[b] = s[511];
}

// single block: exclusive scan of 391 bucket totals -> bucket_base[0..NB]
__global__ void __launch_bounds__(512) bucket_scan(const int* __restrict__ btot,
                                                   int* __restrict__ bucket_base) {
    __shared__ int s[512];
    int t = threadIdx.x;
    int orig = t < NB ? btot[t] : 0;
    s[t] = orig;
    __syncthreads();
    for (int o = 1; o < 512; o <<= 1) {
        int v = t >= o ? s[t - o] : 0;
        __syncthreads();
        s[t] += v;
        __syncthreads();
    }
    if (t < NB) bucket_base[t] = s[t] - orig;
    if (t == NB - 1) bucket_base[NB] = s[t];
}

// stage edges into bucket regions at precomputed (chunk-ordered) offsets.
__global__ void __launch_bounds__(256) bin_stage(const int* __restrict__ dst,
                                                 const int* __restrict__ src,
                                                 const float* __restrict__ ew,
                                                 const int* __restrict__ chunkoff,
                                                 const int* __restrict__ bucket_base,
                                                 int4* __restrict__ staged, int e) {
    __shared__ int base[NB];
    __shared__ int lcur[NB];
    int t = threadIdx.x, c = blockIdx.x;
    int e0 = c * CHSZ;
    int e1 = e0 + CHSZ; if (e1 > e) e1 = e;
    for (int j = t; j < NB; j += 256) {
        base[j] = bucket_base[j] + chunkoff[j * NCHUNK + c];
        lcur[j] = 0;
    }
    __syncthreads();
    for (int i = e0 + t; i < e1; i += 256) {
        int d = dst[i];
        int bin = d >> 8;
        int r = atomicAdd(&lcur[bin], 1);
        staged[(size_t)(base[bin] + r)] = make_int4(d, i, src[i], __float_as_int(ew[i]));
    }
}

// one block per bucket, two passes over its contiguous staged region:
// pass 1 builds the per-node histogram/scan in LDS and emits rowptr;
// pass 2 scatters into the bucket's ~48 KB window. No global atomics.
__global__ void __launch_bounds__(256) bin_scatter2(const int4* __restrict__ staged,
                                                    const int* __restrict__ bucket_base,
                                                    int* __restrict__ rowptr,
                                                    int* __restrict__ col,
                                                    float* __restrict__ ewp,
                                                    int* __restrict__ eorig, int n) {
    __shared__ int sc[256];
    __shared__ int cur[256];
    int b = blockIdx.x, t = threadIdx.x;
    int s0 = bucket_base[b];
    int s1 = bucket_base[b + 1];
    sc[t] = 0;
    __syncthreads();
    for (int i = s0 + t; i < s1; i += 256)
        atomicAdd(&sc[staged[(size_t)i].x & 255], 1);
    __syncthreads();
    int val = sc[t];
    for (int o = 1; o < 256; o <<= 1) {
        int u = t >= o ? sc[t - o] : 0;
        __syncthreads();
        sc[t] += u;
        __syncthreads();
    }
    int start = s0 + sc[t] - val;
    cur[t] = start;
    int node = (b << 8) + t;
    if (node < n) rowptr[node] = start;
    if (b == NB - 1 && t == 0) rowptr[n] = s1;
    __syncthreads();
    for (int i = s0 + t; i < s1; i += 256) {
        int4 v = staged[(size_t)i];
        int p = atomicAdd(&cur[v.x & 255], 1);
        col[p] = v.z;
        ewp[p] = __int_as_float(v.w);
        eorig[p] = v.y;
    }
}

// stable order: sort each row's slots by original edge index (input is nearly
// sorted -> insertion sort ~O(d)). Guarantees numpy edge-order accumulation.
__global__ void sort_rows(const int* __restrict__ rowptr, int* __restrict__ col,
                          float* __restrict__ ewp, int* __restrict__ eorig, int n) {
    int i = blockIdx.x * blockDim.x + threadIdx.x;
    if (i >= n) return;
    int r0 = rowptr[i], r1 = rowptr[i + 1];
    for (int a = r0 + 1; a < r1; ++a) {
        int ke = eorig[a]; int kc = col[a]; float kw = ewp[a];
        int b = a - 1;
        while (b >= r0 && eorig[b] > ke) {
            eorig[b + 1] = eorig[b]; col[b + 1] = col[b]; ewp[b + 1] = ewp[b];
            --b;
        }
        eorig[b + 1] = ke; col[b + 1] = kc; ewp[b + 1] = kw;
    }
}

__global__ void deg_dinv(const int* __restrict__ rowptr, const float* __restrict__ ewp,
                         float* __restrict__ dinv, int n) {
    int i = blockIdx.x * blockDim.x + threadIdx.x;
    if (i < n) {
        float s = 0.0f;
        int r1 = rowptr[i + 1];
        for (int e = rowptr[i]; e < r1; ++e) s += ewp[e];
        dinv[i] = 1.0f / sqrtf(s + 1.0f);
    }
}

__global__ void enorm_csr(const int* __restrict__ rowptr, const int* __restrict__ col,
                          const float* __restrict__ ewp, const float* __restrict__ dinv,
                          float* __restrict__ enormp, int n) {
    int i = blockIdx.x * blockDim.x + threadIdx.x;
    if (i < n) {
        float di = dinv[i];
        int r1 = rowptr[i + 1];
        for (int e = rowptr[i]; e < r1; ++e)
            enormp[e] = dinv[col[e]] * ewp[e] * di;
    }
}

// ---------------- register-tiled GEMM: out[n,64] = X[n,Kd] @ W[Kd,64] ----------
template<int Kd>
__global__ void __launch_bounds__(256) gemm_tile(const float* __restrict__ X,
                                                 const float* __restrict__ W,
                                                 float* __restrict__ out, int n) {
    __shared__ float sW[Kd * 64];
    const int tid = threadIdx.x;
    for (int t = tid; t < Kd * 16; t += 256)
        ((float4*)sW)[t] = ((const float4*)W)[t];
    __syncthreads();

    const int cq = tid >> 6;
    const int rg = tid & 63;
    const int row0 = blockIdx.x * 256 + rg * 4;
    const float4* sW4 = (const float4*)sW;

    float4 acc[4][4];
    #pragma unroll
    for (int r = 0; r < 4; ++r)
        #pragma unroll
        for (int c = 0; c < 4; ++c) acc[r][c] = make_float4(0.f, 0.f, 0.f, 0.f);

    int rl[4];
    #pragma unroll
    for (int r = 0; r < 4; ++r) {
        int rr = row0 + r;
        rl[r] = rr < n ? rr : (n - 1);
    }

    for (int k0 = 0; k0 < Kd; k0 += 8) {
        float4 xa[4][2];
        #pragma unroll
        for (int r = 0; r < 4; ++r) {
            const float4* xp = (const float4*)(X + (size_t)rl[r] * Kd + k0);
            xa[r][0] = xp[0];
            xa[r][1] = xp[1];
        }
        #pragma unroll
        for (int kk = 0; kk < 8; ++kk) {
            float xk[4];
            #pragma unroll
            for (int r = 0; r < 4; ++r) {
                float4 h = xa[r][kk >> 2];
                xk[r] = (kk & 3) == 0 ? h.x : (kk & 3) == 1 ? h.y : (kk & 3) == 2 ? h.z : h.w;
            }
            #pragma unroll
            for (int c = 0; c < 4; ++c) {
                float4 w4 = sW4[(k0 + kk) * 16 + cq * 4 + c];
                #pragma unroll
                for (int r = 0; r < 4; ++r) {
                    acc[r][c].x += xk[r] * w4.x;
                    acc[r][c].y += xk[r] * w4.y;
                    acc[r][c].z += xk[r] * w4.z;
                    acc[r][c].w += xk[r] * w4.w;
                }
            }
        }
    }

    #pragma unroll
    for (int r = 0; r < 4; ++r) {
        int rr = row0 + r;
        if (rr < n) {
            float4* op = (float4*)(out + (size_t)rr * 64 + cq * 16);
            #pragma unroll
            for (int c = 0; c < 4; ++c) op[c] = acc[r][c];
        }
    }
}

// -------- fused CSR aggregation (64 feats): one wave per dst row, lane = feat --------
__global__ void __launch_bounds__(256) agg64_fused(const int* __restrict__ rowptr,
                                                   const int* __restrict__ col,
                                                   const float* __restrict__ enormp,
                                                   const float* __restrict__ hpre,
                                                   const float* __restrict__ dinv,
                                                   const float* __restrict__ bias,
                                                   float* __restrict__ hout, int n) {
    int gid = blockIdx.x * 256 + threadIdx.x;
    int row = gid >> 6;
    int lane = gid & 63;
    if (row >= n) return;
    int r0 = rowptr[row], r1 = rowptr[row + 1];
    float acc = 0.0f;
    for (int base = r0; base < r1; base += 64) {
        int e = base + lane;
        int cv = 0; float ev = 0.0f;
        if (e < r1) { cv = col[e]; ev = enormp[e]; }
        int m = r1 - base; if (m > 64) m = 64;
        int j = 0;
        for (; j + 8 <= m; j += 8) {
            int   s0 = __shfl(cv, j, 64),     s1 = __shfl(cv, j + 1, 64);
            int   s2 = __shfl(cv, j + 2, 64), s3 = __shfl(cv, j + 3, 64);
            int   s4 = __shfl(cv, j + 4, 64), s5 = __shfl(cv, j + 5, 64);
            int   s6 = __shfl(cv, j + 6, 64), s7 = __shfl(cv, j + 7, 64);
            float c0 = __shfl(ev, j, 64),     c1 = __shfl(ev, j + 1, 64);
            float c2 = __shfl(ev, j + 2, 64), c3 = __shfl(ev, j + 3, 64);
            float c4 = __shfl(ev, j + 4, 64), c5 = __shfl(ev, j + 5, 64);
            float c6 = __shfl(ev, j + 6, 64), c7 = __shfl(ev, j + 7, 64);
            float v0 = hpre[(size_t)s0 * 64 + lane];
            float v1 = hpre[(size_t)s1 * 64 + lane];
            float v2 = hpre[(size_t)s2 * 64 + lane];
            float v3 = hpre[(size_t)s3 * 64 + lane];
            float v4 = hpre[(size_t)s4 * 64 + lane];
            float v5 = hpre[(size_t)s5 * 64 + lane];
            float v6 = hpre[(size_t)s6 * 64 + lane];
            float v7 = hpre[(size_t)s7 * 64 + lane];
            acc += c0 * v0; acc += c1 * v1; acc += c2 * v2; acc += c3 * v3;
            acc += c4 * v4; acc += c5 * v5; acc += c6 * v6; acc += c7 * v7;
        }
        for (; j + 4 <= m; j += 4) {
            int   s0 = __shfl(cv, j, 64),     s1 = __shfl(cv, j + 1, 64);
            int   s2 = __shfl(cv, j + 2, 64), s3 = __shfl(cv, j + 3, 64);
            float c0 = __shfl(ev, j, 64),     c1 = __shfl(ev, j + 1, 64);
            float c2 = __shfl(ev, j + 2, 64), c3 = __shfl(ev, j + 3, 64);
            float v0 = hpre[(size_t)s0 * 64 + lane];
            float v1 = hpre[(size_t)s1 * 64 + lane];
            float v2 = hpre[(size_t)s2 * 64 + lane];
            float v3 = hpre[(size_t)s3 * 64 + lane];
            acc += c0 * v0; acc += c1 * v1; acc += c2 * v2; acc += c3 * v3;
        }
        for (; j < m; ++j) {
            int s = __shfl(cv, j, 64);
            float coef = __shfl(ev, j, 64);
            acc += coef * hpre[(size_t)s * 64 + lane];
        }
    }
    float dv = dinv[row];
    hout[gid] = tanhf(acc + dv * dv * hpre[(size_t)row * 64 + lane] + bias[lane]);
}

// ---------------- h2 @ W2 (64 -> 1), one wave per row ----------------
__global__ void gemv64(const float* __restrict__ h, const float* __restrict__ w,
                       float* __restrict__ out, int n) {
    int gid = blockIdx.x * blockDim.x + threadIdx.x;
    int row = gid >> 6;
    int lane = gid & 63;
    if (row >= n) return;
    float v = h[(size_t)row * 64 + lane] * w[lane];
    for (int off = 32; off > 0; off >>= 1) v += __shfl_down(v, off, 64);
    if (lane == 0) out[row] = v;
}

// -------- fused CSR aggregation (1 feat): one thread per dst row --------
__global__ void agg1_fused(const int* __restrict__ rowptr, const int* __restrict__ col,
                           const float* __restrict__ enormp, const float* __restrict__ hpre3,
                           const float* __restrict__ dinv, const float* __restrict__ b2,
                           float* __restrict__ h3, int n) {
    int i = blockIdx.x * blockDim.x + threadIdx.x;
    if (i >= n) return;
    float acc = 0.0f;
    int r1 = rowptr[i + 1];
    for (int e = rowptr[i]; e < r1; ++e) acc += enormp[e] * hpre3[col[e]];
    float dv = dinv[i];
    h3[i] = tanhf(acc + dv * dv * hpre3[i] + b2[0]);
}

// ---------------- group compaction: deterministic counting sort ----------------
__global__ void __launch_bounds__(256) grp_hist(const int* __restrict__ group,
                                                int* __restrict__ bcnt, int n) {
    __shared__ int lh[NG];
    int b = blockIdx.x, t = threadIdx.x;
    if (t < NG) lh[t] = 0;
    __syncthreads();
    int i = b * 256 + t;
    if (i < n) atomicAdd(&lh[group[i]], 1);
    __syncthreads();
    if (t < NG) bcnt[t * NBLK + b] = lh[t];
}

__global__ void __launch_bounds__(512) grp_scan(const int* __restrict__ bcnt,
                                                int* __restrict__ boff,
                                                int* __restrict__ cnt) {
    __shared__ int s[512];
    int g = blockIdx.x, t = threadIdx.x;
    int orig = t < NBLK ? bcnt[g * NBLK + t] : 0;
    s[t] = orig;
    __syncthreads();
    for (int o = 1; o < 512; o <<= 1) {
        int v = t >= o ? s[t - o] : 0;
        __syncthreads();
        s[t] += v;
        __syncthreads();
    }
    if (t < NBLK) boff[g * NBLK + t] = s[t] - orig;
    if (t == 511) cnt[g] = s[NBLK - 1] > CAP ? CAP : s[NBLK - 1];
}

__global__ void __launch_bounds__(256) grp_fill(const int* __restrict__ group,
                                                const int* __restrict__ boff,
                                                int* __restrict__ lists, int n) {
    __shared__ int lcur[NG];
    int b = blockIdx.x, t = threadIdx.x;
    if (t < NG) lcur[t] = 0;
    __syncthreads();
    int i = b * 256 + t;
    if (i < n) {
        int g = group[i];
        int p = atomicAdd(&lcur[g], 1);
        int pos = boff[g * NBLK + b] + p;
        if (pos < CAP) lists[g * CAP + pos] = i;
    }
}

// ---------------- per-group top-K by h3: iterative selection in registers ----------
__device__ __forceinline__ unsigned int fkey(float v) {
    unsigned int b = __float_as_uint(v);
    return (b & 0x80000000u) ? ~b : (b | 0x80000000u);
}

__global__ void __launch_bounds__(256) topk_kernel(const int* __restrict__ cnt,
                                                   const int* __restrict__ lists,
                                                   const float* __restrict__ h3,
                                                   int* __restrict__ topk) {
    __shared__ unsigned long long wmax[4];
    __shared__ unsigned long long winner;
    int g = blockIdx.x;
    int tid = threadIdx.x;
    int lane = tid & 63, wid = tid >> 6;
    int c = cnt[g];
    if (c > CAP) c = CAP;

    unsigned long long key[SLOTS];
    #pragma unroll
    for (int s = 0; s < SLOTS; ++s) {
        int e = s * 256 + tid;
        if (e < c) {
            int node = lists[g * CAP + e];
            key[s] = ((unsigned long long)fkey(h3[node]) << 32) | (unsigned int)(~node);
        } else {
            key[s] = 0ull;
        }
    }

    for (int k = 0; k < KTOP; ++k) {
        unsigned long long best = 0ull;
        #pragma unroll
        for (int s = 0; s < SLOTS; ++s) best = key[s] > best ? key[s] : best;
        #pragma unroll
        for (int off = 32; off > 0; off >>= 1) {
            unsigned long long o = __shfl_down(best, off, 64);
            best = o > best ? o : best;
        }
        if (lane == 0) wmax[wid] = best;
        __syncthreads();
        if (tid == 0) {
            unsigned long long b = wmax[0];
            for (int w = 1; w < 4; ++w) b = wmax[w] > b ? wmax[w] : b;
            winner = b;
            topk[g * KTOP + k] = ~(int)(unsigned int)b;
        }
        __syncthreads();
        unsigned long long w = winner;
        #pragma unroll
        for (int s = 0; s < SLOTS; ++s) if (key[s] == w) key[s] = 0ull;
        __syncthreads();
    }
}

// ---------------- fused sort-pool gather + conv1 + maxpool + conv2 ----------------
__global__ void __launch_bounds__(256) pool_conv(const float* __restrict__ h1,
                                                 const float* __restrict__ h2,
                                                 const float* __restrict__ h3,
                                                 const int* __restrict__ topk,
                                                 const float* __restrict__ c1w,
                                                 const float* __restrict__ c1b,
                                                 const float* __restrict__ c2w,
                                                 const float* __restrict__ c2b,
                                                 float* __restrict__ out) {
    __shared__ float sfeat[KTOP * DFLAT];
    __shared__ float sy[NC1 * KTOP];
    __shared__ float sm[NC1 * (KTOP / 2)];
    int g = blockIdx.x;
    int tid = threadIdx.x;

    for (int t = tid; t < KTOP * DFLAT; t += blockDim.x) {
        int k = t / DFLAT, d = t - k * DFLAT;
        int node = topk[g * KTOP + k];
        float v;
        if (d < 64)        v = h1[(size_t)node * 64 + d];
        else if (d < 128)  v = h2[(size_t)node * 64 + (d - 64)];
        else               v = h3[node];
        sfeat[t] = v;
    }
    __syncthreads();

    for (int t = tid; t < NC1 * KTOP; t += blockDim.x) {
        int c = t / KTOP, k = t - c * KTOP;
        float acc = c1b[c];
        const float* w = c1w + c * DFLAT;
        const float* f = sfeat + k * DFLAT;
        for (int d = 0; d < DFLAT; ++d) acc += f[d] * w[d];
        sy[c * KTOP + k] = fmaxf(acc, 0.0f);
    }
    __syncthreads();

    for (int t = tid; t < NC1 * (KTOP / 2); t += blockDim.x) {
        int c = t / (KTOP / 2), j = t - c * (KTOP / 2);
        sm[t] = fmaxf(sy[c * KTOP + 2 * j], sy[c * KTOP + 2 * j + 1]);
    }
    __syncthreads();

    for (int t = tid; t < NC2 * TOUT; t += blockDim.x) {
        int c2 = t / TOUT, tt = t - c2 * TOUT;
        float acc = c2b[c2];
        for (int c1i = 0; c1i < NC1; ++c1i) {
            const float* w = c2w + (c2 * NC1 + c1i) * KSZ;
            const float* m = sm + c1i * (KTOP / 2) + tt;
            for (int s = 0; s < KSZ; ++s) acc += m[s] * w[s];
        }
        out[g * NC2 * TOUT + t] += fmaxf(acc, 0.0f);
    }
}

// ---------------- host ----------------
static inline size_t align256(size_t x) { return (x + 255) & ~(size_t)255; }

extern "C" void kernel_launch(void* const* d_in, const int* in_sizes, int n_in,
                              void* d_out, int out_size, void* d_ws, size_t ws_size,
                              hipStream_t stream) {
    const float* x       = (const float*)d_in[0];
    const int*   eidx    = (const int*)d_in[1];    // [R,2,E]
    const float* ew      = (const float*)d_in[2];  // [R,E]
    const int*   group   = (const int*)d_in[3];    // [N]
    const float* W0      = (const float*)d_in[4];  // [R,128,64]
    const float* b0      = (const float*)d_in[5];
    const float* W1      = (const float*)d_in[6];  // [R,64,64]
    const float* b1      = (const float*)d_in[7];
    const float* W2      = (const float*)d_in[8];  // [R,64,1]
    const float* b2      = (const float*)d_in[9];
    const float* c1w     = (const float*)d_in[10];
    const float* c1b     = (const float*)d_in[11];
    const float* c2w     = (const float*)d_in[12];
    const float* c2b     = (const float*)d_in[13];
    float* out = (float*)d_out;

    char* ws = (char*)d_ws;
    size_t off = 0;
    float* dinv    = (float*)(ws + off); off = align256(off + (size_t)N_NODES * 4);
    int*   rowptr  = (int*)(ws + off);   off = align256(off + (size_t)(N_NODES + 1) * 4);
    int*   col     = (int*)(ws + off);   off = align256(off + (size_t)E_EDGES * 4);
    float* ewp     = (float*)(ws + off); off = align256(off + (size_t)E_EDGES * 4);
    int*   eorig   = (int*)(ws + off);   off = align256(off + (size_t)E_EDGES * 4);
    float* enormp  = (float*)(ws + off); off = align256(off + (size_t)E_EDGES * 4);
    float* hpre    = (float*)(ws + off); off = align256(off + (size_t)N_NODES * 64 * 4);
    float* h1      = (float*)(ws + off); off = align256(off + (size_t)N_NODES * 64 * 4);
    float* h2      = (float*)(ws + off); off = align256(off + (size_t)N_NODES * 64 * 4);
    float* hpre3   = (float*)(ws + off); off = align256(off + (size_t)N_NODES * 4);
    float* h3      = (float*)(ws + off); off = align256(off + (size_t)N_NODES * 4);
    int*   cnt     = (int*)(ws + off);   off = align256(off + (size_t)NG * 4);
    int*   lists   = (int*)(ws + off);   off = align256(off + (size_t)NG * CAP * 4);
    int*   topk    = (int*)(ws + off);   off = align256(off + (size_t)NG * KTOP * 4);
    int*   bcnt    = (int*)(ws + off);   off = align256(off + (size_t)NG * NBLK * 4);
    int*   boff    = (int*)(ws + off);   off = align256(off + (size_t)NG * NBLK * 4);
    int*   chist   = (int*)(ws + off);   off = align256(off + (size_t)NB * NCHUNK * 4);
    int*   chunkoff= (int*)(ws + off);   off = align256(off + (size_t)NB * NCHUNK * 4);
    int*   btot    = (int*)(ws + off);   off = align256(off + (size_t)(NB + 1) * 4);
    int*   bucket_base = (int*)(ws + off); off = align256(off + (size_t)(NB + 1) * 4);
    int4*  staged  = (int4*)(ws + off);  off = align256(off + (size_t)E_EDGES * 16);
    (void)ws_size;

    const int B = 256;
    const int nOut = NG * NC2 * TOUT;
    const int gN   = (N_NODES + B - 1) / B;           // 391
    const int gW   = (N_NODES * 64 + B - 1) / B;      // 25000
    const int gT   = (N_NODES + 255) / 256;           // gemm_tile

    zero_f32<<<(nOut + B - 1) / B, B, 0, stream>>>(out, nOut);

    // group compaction: deterministic counting sort, once per launch
    grp_hist<<<NBLK, B, 0, stream>>>(group, bcnt, N_NODES);
    grp_scan<<<NG, 512, 0, stream>>>(bcnt, boff, cnt);
    grp_fill<<<NBLK, B, 0, stream>>>(group, boff, lists, N_NODES);

    for (int r = 0; r < R_REL; ++r) {
        const int* src = eidx + (size_t)r * 2 * E_EDGES;
        const int* dst = src + E_EDGES;
        const float* ewr = ew + (size_t)r * E_EDGES;

        // ---- binned permutation build (deterministic chunk order, fused rowptr) ----
        bin_hist<<<NCHUNK, B, 0, stream>>>(dst, chist, E_EDGES);
        bin_scan<<<NB, 512, 0, stream>>>(chist, chunkoff, btot);
        bucket_scan<<<1, 512, 0, stream>>>(btot, bucket_base);
        bin_stage<<<NCHUNK, B, 0, stream>>>(dst, src, ewr, chunkoff, bucket_base,
                                            staged, E_EDGES);
        bin_scatter2<<<NB, B, 0, stream>>>(staged, bucket_base, rowptr,
                                           col, ewp, eorig, N_NODES);
        sort_rows<<<gN, B, 0, stream>>>(rowptr, col, ewp, eorig, N_NODES);
        deg_dinv<<<gN, B, 0, stream>>>(rowptr, ewp, dinv, N_NODES);
        enorm_csr<<<gN, B, 0, stream>>>(rowptr, col, ewp, dinv, enormp, N_NODES);

        // layer 1
        gemm_tile<128><<<gT, B, 0, stream>>>(x, W0 + (size_t)r * 128 * 64, hpre, N_NODES);
        agg64_fused<<<gW, B, 0, stream>>>(rowptr, col, enormp, hpre, dinv,
                                          b0 + (size_t)r * 64, h1, N_NODES);
        // layer 2
        gemm_tile<64><<<gT, B, 0, stream>>>(h1, W1 + (size_t)r * 64 * 64, hpre, N_NODES);
        agg64_fused<<<gW, B, 0, stream>>>(rowptr, col, enormp, hpre, dinv,
                                          b1 + (size_t)r * 64, h2, N_NODES);
        // layer 3
        gemv64<<<gW, B, 0, stream>>>(h2, W2 + (size_t)r * 64, hpre3, N_NODES);
        agg1_fused<<<gN, B, 0, stream>>>(rowptr, col, enormp, hpre3, dinv, b2 + r, h3, N_NODES);

        // sort pooling + convs
        topk_kernel<<<NG, B, 0, stream>>>(cnt, lists, h3, topk);
        pool_conv<<<NG, B, 0, stream>>>(h1, h2, h3, topk, c1w, c1b, c2w, c2b, out);
    }
}